// Round 10
// baseline (162.007 us; speedup 1.0000x reference)
//
#include <hip/hip_runtime.h>
#include <stdint.h>

typedef __attribute__((ext_vector_type(8))) short short8;       // 8 x bf16
typedef __attribute__((ext_vector_type(4))) float f32x4;
typedef __attribute__((ext_vector_type(4))) unsigned short ushort4_;
typedef __attribute__((ext_vector_type(4))) unsigned int uint4_;

#define MFMA16(a, b, c) __builtin_amdgcn_mfma_f32_16x16x32_bf16((a), (b), (c), 0, 0, 0)

static __device__ __forceinline__ unsigned short f2bf(float f) {
    unsigned u = __float_as_uint(f);
    u += 0x7fffu + ((u >> 16) & 1u);   // RNE
    return (unsigned short)(u >> 16);
}

static __device__ __forceinline__ float bf2f(unsigned short u) {
    return __uint_as_float(((unsigned)u) << 16);
}

static __device__ __forceinline__ float exp2_fast(float x) {
#if __has_builtin(__builtin_amdgcn_exp2f)
    return __builtin_amdgcn_exp2f(x);
#else
    return exp2f(x);
#endif
}

static __device__ __forceinline__ unsigned cvt_pk(float lo, float hi) {
    unsigned r;
    asm("v_cvt_pk_bf16_f32 %0, %1, %2" : "=v"(r) : "v"(lo), "v"(hi));
    return r;
}

static __device__ __forceinline__ short8 pack8(float a0, float a1, float a2, float a3,
                                               float a4, float a5, float a6, float a7) {
    union { uint4_ u; short8 s; } c;
    c.u[0] = cvt_pk(a0, a1); c.u[1] = cvt_pk(a2, a3);
    c.u[2] = cvt_pk(a4, a5); c.u[3] = cvt_pk(a6, a7);
    return c.s;
}

#define GLOAD16(SRC, DSTPTR) __builtin_amdgcn_global_load_lds(                       \
    (const __attribute__((address_space(1))) void*)(SRC),                            \
    (__attribute__((address_space(3))) void*)(DSTPTR), 16, 0, 0)

// ---------------------------------------------------------------------------
// Kernel 0: W (3 heads, f32) -> bf16, contiguous Wb[3][128][1024]
// ---------------------------------------------------------------------------
__global__ __launch_bounds__(256) void wcvt_kernel(
    const float* __restrict__ Wq, const float* __restrict__ Wk, const float* __restrict__ Wv,
    unsigned short* __restrict__ Wb)
{
    const int hd = blockIdx.y;
    const float* W = (hd == 0) ? Wq : ((hd == 1) ? Wk : Wv);
    const int idx = (blockIdx.x * 256 + threadIdx.x) * 4;
    f32x4 v = *(const f32x4*)(W + idx);
    ushort4_ o;
#pragma unroll
    for (int j = 0; j < 4; ++j) o[j] = f2bf(v[j]);
    *(ushort4_*)(Wb + (size_t)hd * 131072 + idx) = o;
}

// ---------------------------------------------------------------------------
// Kernel 1: QKV projection (r9 verbatim — measured improvement).
// Per-head blocks: grid (128, 3), M-tile 64, 4 waves x 16 rows. K-step 64,
// 16 steps, ONE __syncthreads per step. W via global_load_lds w16 (swizzled
// source); X f32 reg-staged. LDS 48KB -> 3 blocks/CU.
// ---------------------------------------------------------------------------
__global__ __launch_bounds__(256) void qkv_kernel(
    const float* __restrict__ X, const unsigned short* __restrict__ Wb,
    unsigned short* __restrict__ Qs, unsigned short* __restrict__ Kb, unsigned short* __restrict__ Vt)
{
    __shared__ __align__(16) char lds[49152];   // X dbuf 2x8KB @0; W dbuf 2x16KB @16384
    const int tid  = threadIdx.x;
    const int lane = tid & 63, wid = tid >> 6;
    const int lrow = lane & 15, lgrp = lane >> 4;
    const int m0   = blockIdx.x * 64;
    const int hd   = blockIdx.y;
    const unsigned short* W = Wb + (size_t)hd * 131072;

    const char* wsrc[4];
    int wdoff[4];
#pragma unroll
    for (int g = 0; g < 4; ++g) {
        const int slot = g * 256 + tid;          // 0..1023
        const int row = slot >> 3, c16 = slot & 7;
        wsrc[g] = (const char*)(W + (size_t)row * 1024) + 16 * (c16 ^ (row & 7));
        wdoff[g] = g * 4096 + wid * 1024;
    }
    const int xrow = tid >> 2, xseg = tid & 3;   // 64 rows x 4 segs x 16 f32
    const float* xbase = X + (size_t)(m0 + xrow) * 1024 + xseg * 16;
    const int xsw = (xrow & 7) << 4;
    const int xwoff0 = xrow * 128 + (((xseg * 2)     * 16) ^ xsw);
    const int xwoff1 = xrow * 128 + (((xseg * 2 + 1) * 16) ^ xsw);

    f32x4 acc[8];
#pragma unroll
    for (int b = 0; b < 8; b++) acc[b] = (f32x4)0.0f;

#pragma unroll
    for (int g = 0; g < 4; ++g) GLOAD16(wsrc[g], lds + 16384 + wdoff[g]);
    {
        f32x4 x0 = *(const f32x4*)(xbase);
        f32x4 x1 = *(const f32x4*)(xbase + 4);
        f32x4 x2 = *(const f32x4*)(xbase + 8);
        f32x4 x3 = *(const f32x4*)(xbase + 12);
        *(short8*)(lds + xwoff0) = pack8(x0[0], x0[1], x0[2], x0[3], x1[0], x1[1], x1[2], x1[3]);
        *(short8*)(lds + xwoff1) = pack8(x2[0], x2[1], x2[2], x2[3], x3[0], x3[1], x3[2], x3[3]);
    }
    __syncthreads();

    for (int ks = 0; ks < 16; ++ks) {
        const int buf = ks & 1;
        f32x4 nx0, nx1, nx2, nx3;
        if (ks < 15) {
#pragma unroll
            for (int g = 0; g < 4; ++g)
                GLOAD16(wsrc[g] + (size_t)(ks + 1) * 128, lds + 16384 + (buf ^ 1) * 16384 + wdoff[g]);
            nx0 = *(const f32x4*)(xbase + (ks + 1) * 64);
            nx1 = *(const f32x4*)(xbase + (ks + 1) * 64 + 4);
            nx2 = *(const f32x4*)(xbase + (ks + 1) * 64 + 8);
            nx3 = *(const f32x4*)(xbase + (ks + 1) * 64 + 12);
        }
        const char* xb  = lds + buf * 8192;
        const char* wbl = lds + 16384 + buf * 16384;
        __builtin_amdgcn_s_setprio(1);
#pragma unroll
        for (int kc = 0; kc < 2; ++kc) {
            const int arow = wid * 16 + lrow;
            const int koff = (kc * 64 + lgrp * 16) ^ ((lrow & 7) << 4);
            short8 a = *(const short8*)(xb + arow * 128 + koff);
#pragma unroll
            for (int cf = 0; cf < 8; ++cf) {
                const int n = cf * 16 + lrow;
                short8 b = *(const short8*)(wbl + n * 128 + koff);
                acc[cf] = MFMA16(a, b, acc[cf]);
            }
        }
        __builtin_amdgcn_s_setprio(0);
        if (ks < 15) {
            *(short8*)(lds + (buf ^ 1) * 8192 + xwoff0) =
                pack8(nx0[0], nx0[1], nx0[2], nx0[3], nx1[0], nx1[1], nx1[2], nx1[3]);
            *(short8*)(lds + (buf ^ 1) * 8192 + xwoff1) =
                pack8(nx2[0], nx2[1], nx2[2], nx2[3], nx3[0], nx3[1], nx3[2], nx3[3]);
        }
        __syncthreads();
    }

    const float qscale = 0.12752039f;   // log2(e)/sqrt(128)
    if (hd < 2) {
        unsigned short* dst = (hd == 0) ? Qs : Kb;
        const float sc = (hd == 0) ? qscale : 1.0f;
#pragma unroll
        for (int cf = 0; cf < 8; ++cf)
#pragma unroll
            for (int r = 0; r < 4; ++r) {
                const int row = m0 + wid * 16 + lgrp * 4 + r;
                const int col = cf * 16 + lrow;
                dst[(size_t)row * 128 + col] = f2bf(acc[cf][r] * sc);
            }
    } else {
#pragma unroll
        for (int cf = 0; cf < 8; ++cf) {
            const int row0 = m0 + wid * 16 + lgrp * 4;
            const int col  = cf * 16 + lrow;
            ushort4_ v;
#pragma unroll
            for (int r = 0; r < 4; r++) v[r] = f2bf(acc[cf][r]);
            *(ushort4_*)(Vt + (size_t)col * 8192 + row0) = v;
        }
    }
}

// ---------------------------------------------------------------------------
// Kernel 2: flash-attention partial, occupancy-first restructure:
//   16 q/wave (halved per-wave state), KVBLK=64, 16 iters.
//   K: LDS dbuf 2x16KB via global_load_lds (sigma+swizzle source, r7-verified).
//   V: DIRECT global->reg in two staged halves (no LDS reads for PV; the
//      16KB V tile is read by 4 lockstep waves -> L1-served).
//   Simple r7-style loop, one __syncthreads per iter (pipeline was null, r9).
// grid 1024 = 128 q-tiles(64 rows) x 8 kv-splits(1024). Block 256 = 4 waves.
// LDS 32KB, VGPR ~150-170 -> target 3 blocks/CU (12 waves/CU, 1.5x r9).
// ---------------------------------------------------------------------------
__global__ __launch_bounds__(256) void attn_kernel(
    const unsigned short* __restrict__ Qs,
    const unsigned short* __restrict__ Kb,
    const unsigned short* __restrict__ Vt,
    unsigned short* __restrict__ partO, float* __restrict__ partML)
{
    __shared__ __align__(16) char lds[32768];   // K dbuf 2 x 16KB
    const int tid = threadIdx.x, lane = tid & 63, wid = tid >> 6;
    const int lrow = lane & 15, lgrp = lane >> 4;
    const int qtile = blockIdx.x >> 3, sp = blockIdx.x & 7;
    const int qb = qtile * 64 + wid * 16;
    const int kvstart = sp * 1024;

    // --- K staging: 4 glds/thread; 64 sigma-permuted rows, swizzled source ---
    const char* ksrc[4];
    int kdoff[4];
#pragma unroll
    for (int g = 0; g < 4; ++g) {
        const int slot = g * 16 + wid * 4 + lgrp;            // 0..63
        const int krow = (slot & 32) | (((slot >> 2) & 3) << 3)
                       | (((slot >> 4) & 1) << 2) | (slot & 3);
        ksrc[g] = (const char*)Kb + (size_t)(kvstart + krow) * 256
                + 16 * (lrow ^ (slot & 15));
        kdoff[g] = g * 4096 + wid * 1024;                    // + buf*16384
    }
    // --- V fragment base (direct global -> reg; L1-shared across waves) ---
    const char* vbyte = (const char*)Vt + (size_t)lrow * 16384 + (size_t)kvstart * 2 + lgrp * 16;

    // Q fragments: lane holds Q[qb + lrow][c*32 + lgrp*8 ..]
    short8 qf[4];
#pragma unroll
    for (int c = 0; c < 4; ++c)
        qf[c] = *(const short8*)(Qs + (size_t)(qb + lrow) * 128 + c * 32 + lgrp * 8);

    f32x4 o[8];
#pragma unroll
    for (int i = 0; i < 8; ++i) o[i] = (f32x4)0.0f;
    float m = -1e30f, l = 0.0f;

    // prologue: K(0) -> buf 0 (implicit full drain via __syncthreads)
#pragma unroll
    for (int g = 0; g < 4; ++g) GLOAD16(ksrc[g], lds + kdoff[g]);
    __syncthreads();

    for (int t = 0; t < 16; ++t) {
        const int buf = t & 1;
        const char* kb = lds + buf * 16384;

        // ---- V half 0 (kv 0..31 of tile t): issue now, flies through QK ----
        short8 vr0[8];
#pragma unroll
        for (int df = 0; df < 8; ++df)
            vr0[df] = *(const short8*)(vbyte + (size_t)df * 262144 + t * 128);

        // ---- prefetch K(t+1) into buf^1 (drained by end-of-iter barrier) ----
        if (t < 15) {
#pragma unroll
            for (int g = 0; g < 4; ++g)
                GLOAD16(ksrc[g] + (size_t)(t + 1) * 16384, lds + (buf ^ 1) * 16384 + kdoff[g]);
        }

        // ---- S^T = K Q over 64 kv (exp2 domain; scale folded into Q) ----
        f32x4 s[4];
#pragma unroll
        for (int f = 0; f < 4; ++f) s[f] = (f32x4)0.0f;
        __builtin_amdgcn_s_setprio(1);
#pragma unroll
        for (int f = 0; f < 4; ++f) {
            const int rbase = (f * 16 + lrow) * 256;
            const int swz = lrow << 4;
#pragma unroll
            for (int c = 0; c < 4; ++c) {
                short8 kf = *(const short8*)(kb + rbase + ((c * 64 + lgrp * 16) ^ swz));
                s[f] = MFMA16(kf, qf[c], s[f]);
            }
        }
        __builtin_amdgcn_s_setprio(0);

        // ---- V half 1 (kv 32..63): flies through softmax ----
        short8 vr1[8];
#pragma unroll
        for (int df = 0; df < 8; ++df)
            vr1[df] = *(const short8*)(vbyte + (size_t)df * 262144 + t * 128 + 64);

        // ---- online softmax: lane owns q=lane&15;
        //      kv = (f>>1)*32 + 8*lgrp + 4*(f&1) + r (sigma-matched) ----
        float a0 = fmaxf(fmaxf(s[0][0], s[0][1]), fmaxf(s[0][2], s[0][3]));
        float a1 = fmaxf(fmaxf(s[1][0], s[1][1]), fmaxf(s[1][2], s[1][3]));
        float a2 = fmaxf(fmaxf(s[2][0], s[2][1]), fmaxf(s[2][2], s[2][3]));
        float a3 = fmaxf(fmaxf(s[3][0], s[3][1]), fmaxf(s[3][2], s[3][3]));
        float tm = fmaxf(fmaxf(a0, a1), fmaxf(a2, a3));
        tm = fmaxf(tm, __shfl_xor(tm, 16));
        tm = fmaxf(tm, __shfl_xor(tm, 32));
        if (__any(tm > m + 8.0f)) {   // deferred-max rescale
            const float mn = fmaxf(m, tm);
            const float al = exp2_fast(m - mn);
            m = mn;
            l *= al;
#pragma unroll
            for (int r = 0; r < 4; ++r) {
                const float ar = __shfl(al, lgrp * 4 + r);
#pragma unroll
                for (int df = 0; df < 8; ++df) o[df][r] *= ar;
            }
        }
        float rs = 0.0f;
#pragma unroll
        for (int f = 0; f < 4; ++f)
#pragma unroll
            for (int r = 0; r < 4; ++r) {
                const float p = exp2_fast(s[f][r] - m);
                s[f][r] = p;
                rs += p;
            }
        rs += __shfl_xor(rs, 16);
        rs += __shfl_xor(rs, 32);
        l += rs;
        short8 pa0 = pack8(s[0][0], s[0][1], s[0][2], s[0][3],
                           s[1][0], s[1][1], s[1][2], s[1][3]);
        short8 pa1 = pack8(s[2][0], s[2][1], s[2][2], s[2][3],
                           s[3][0], s[3][1], s[3][2], s[3][3]);

        // ---- O += P V (V from registers; zero LDS reads) ----
        __builtin_amdgcn_s_setprio(1);
#pragma unroll
        for (int df = 0; df < 8; ++df)
            o[df] = MFMA16(pa0, vr0[df], o[df]);
#pragma unroll
        for (int df = 0; df < 8; ++df)
            o[df] = MFMA16(pa1, vr1[df], o[df]);
        __builtin_amdgcn_s_setprio(0);

        __syncthreads();   // drains K(t+1) glds (issued ~full iter ago); buf swap
    }

    // ---- state to row form (row = lgrp*4 + r) ----
    float mr[4], lr_[4];
#pragma unroll
    for (int r = 0; r < 4; ++r) {
        mr[r]  = __shfl(m, lgrp * 4 + r);
        lr_[r] = __shfl(l, lgrp * 4 + r);
    }

    // ---- write bf16 unnormalized partial + f32 (m,l) ----
#pragma unroll
    for (int df = 0; df < 8; ++df)
#pragma unroll
        for (int r = 0; r < 4; ++r) {
            const int qg = qb + lgrp * 4 + r;
            partO[((size_t)sp * 8192 + qg) * 128 + df * 16 + lrow] = f2bf(o[df][r]);
        }
    if (lrow == 0) {
#pragma unroll
        for (int r = 0; r < 4; ++r) {
            const int qg = qb + lgrp * 4 + r;
            partML[((size_t)sp * 8192 + qg) * 2]     = mr[r];
            partML[((size_t)sp * 8192 + qg) * 2 + 1] = lr_[r];
        }
    }
}

// ---------------------------------------------------------------------------
// Kernel 3: merge 8 kv-split bf16 partials and normalize.
// ---------------------------------------------------------------------------
__global__ __launch_bounds__(256) void merge_kernel(
    const unsigned short* __restrict__ partO, const float* __restrict__ partML,
    float* __restrict__ out)
{
    const int gid = blockIdx.x * 256 + threadIdx.x;   // 0..262143
    const int q = gid >> 5, dc = gid & 31;
    float mv[8], lv[8];
#pragma unroll
    for (int spv = 0; spv < 8; ++spv) {
        mv[spv] = partML[((size_t)spv * 8192 + q) * 2];
        lv[spv] = partML[((size_t)spv * 8192 + q) * 2 + 1];
    }
    float M = mv[0];
#pragma unroll
    for (int spv = 1; spv < 8; ++spv) M = fmaxf(M, mv[spv]);
    float e[8], L = 0.f;
#pragma unroll
    for (int spv = 0; spv < 8; ++spv) { e[spv] = exp2_fast(mv[spv] - M); L += lv[spv] * e[spv]; }
    const float inv = 1.0f / L;
    f32x4 r = (f32x4)0.0f;
#pragma unroll
    for (int spv = 0; spv < 8; ++spv) {
        ushort4_ v = *(const ushort4_*)(partO + ((size_t)spv * 8192 + q) * 128 + dc * 4);
#pragma unroll
        for (int k = 0; k < 4; ++k) r[k] += bf2f(v[k]) * e[spv];
    }
#pragma unroll
    for (int k = 0; k < 4; ++k) r[k] *= inv;
    *(f32x4*)(out + (size_t)q * 128 + dc * 4) = r;
}

extern "C" void kernel_launch(void* const* d_in, const int* in_sizes, int n_in,
                              void* d_out, int out_size, void* d_ws, size_t ws_size,
                              hipStream_t stream)
{
    const float* X  = (const float*)d_in[0];
    const float* Wq = (const float*)d_in[1];
    const float* Wk = (const float*)d_in[2];
    const float* Wv = (const float*)d_in[3];

    char* ws = (char*)d_ws;
    const size_t QS_OFF  = 0;                                   // 2 MiB
    const size_t KB_OFF  = QS_OFF + (size_t)8192 * 128 * 2;     // 2 MiB
    const size_t VT_OFF  = KB_OFF + (size_t)8192 * 128 * 2;     // 2 MiB (V transposed)
    const size_t WB_OFF  = VT_OFF + (size_t)8192 * 128 * 2;     // 768 KiB
    const size_t PO_OFF  = WB_OFF + (size_t)3 * 128 * 1024 * 2; // 8*8192*128 bf16 = 16 MiB
    const size_t PML_OFF = PO_OFF + (size_t)8 * 8192 * 128 * 2; // 8*8192*2 f32 = 512 KiB

    unsigned short* Qs  = (unsigned short*)(ws + QS_OFF);
    unsigned short* Kb  = (unsigned short*)(ws + KB_OFF);
    unsigned short* Vt  = (unsigned short*)(ws + VT_OFF);
    unsigned short* Wb  = (unsigned short*)(ws + WB_OFF);
    unsigned short* partO = (unsigned short*)(ws + PO_OFF);
    float* partML = (float*)(ws + PML_OFF);
    float* out = (float*)d_out;

    wcvt_kernel<<<dim3(128, 3), 256, 0, stream>>>(Wq, Wk, Wv, Wb);
    qkv_kernel<<<dim3(128, 3), 256, 0, stream>>>(X, Wb, Qs, Kb, Vt);
    attn_kernel<<<dim3(1024), 256, 0, stream>>>(Qs, Kb, Vt, partO, partML);
    merge_kernel<<<dim3(1024), 256, 0, stream>>>(partO, partML, out);
}

// Round 11
// 88.951 us; speedup vs baseline: 1.8213x; 1.8213x over previous
//
#include <hip/hip_runtime.h>
#include <stdint.h>

typedef __attribute__((ext_vector_type(8))) short short8;       // 8 x bf16
typedef __attribute__((ext_vector_type(4))) float f32x4;
typedef __attribute__((ext_vector_type(4))) unsigned short ushort4_;
typedef __attribute__((ext_vector_type(4))) unsigned int uint4_;

#define MFMA16(a, b, c) __builtin_amdgcn_mfma_f32_16x16x32_bf16((a), (b), (c), 0, 0, 0)

static __device__ __forceinline__ unsigned short f2bf(float f) {
    unsigned u = __float_as_uint(f);
    u += 0x7fffu + ((u >> 16) & 1u);   // RNE
    return (unsigned short)(u >> 16);
}

static __device__ __forceinline__ float bf2f(unsigned short u) {
    return __uint_as_float(((unsigned)u) << 16);
}

static __device__ __forceinline__ float exp2_fast(float x) {
#if __has_builtin(__builtin_amdgcn_exp2f)
    return __builtin_amdgcn_exp2f(x);
#else
    return exp2f(x);
#endif
}

static __device__ __forceinline__ unsigned cvt_pk(float lo, float hi) {
    unsigned r;
    asm("v_cvt_pk_bf16_f32 %0, %1, %2" : "=v"(r) : "v"(lo), "v"(hi));
    return r;
}

static __device__ __forceinline__ short8 pack8(float a0, float a1, float a2, float a3,
                                               float a4, float a5, float a6, float a7) {
    union { uint4_ u; short8 s; } c;
    c.u[0] = cvt_pk(a0, a1); c.u[1] = cvt_pk(a2, a3);
    c.u[2] = cvt_pk(a4, a5); c.u[3] = cvt_pk(a6, a7);
    return c.s;
}

#define GLOAD16(SRC, DSTPTR) __builtin_amdgcn_global_load_lds(                       \
    (const __attribute__((address_space(1))) void*)(SRC),                            \
    (__attribute__((address_space(3))) void*)(DSTPTR), 16, 0, 0)

// ---------------------------------------------------------------------------
// Kernel 0: W (3 heads, f32) -> bf16, contiguous Wb[3][128][1024]
// ---------------------------------------------------------------------------
__global__ __launch_bounds__(256) void wcvt_kernel(
    const float* __restrict__ Wq, const float* __restrict__ Wk, const float* __restrict__ Wv,
    unsigned short* __restrict__ Wb)
{
    const int hd = blockIdx.y;
    const float* W = (hd == 0) ? Wq : ((hd == 1) ? Wk : Wv);
    const int idx = (blockIdx.x * 256 + threadIdx.x) * 4;
    f32x4 v = *(const f32x4*)(W + idx);
    ushort4_ o;
#pragma unroll
    for (int j = 0; j < 4; ++j) o[j] = f2bf(v[j]);
    *(ushort4_*)(Wb + (size_t)hd * 131072 + idx) = o;
}

// ---------------------------------------------------------------------------
// Kernel 1: QKV projection (r9 version — best measured, ~12-13 us).
// Per-head blocks: grid (128, 3), M-tile 64, 4 waves x 16 rows. K-step 64,
// 16 steps, ONE __syncthreads per step. W via global_load_lds w16 (swizzled
// source); X f32 reg-staged (T14). LDS 48KB -> 3 blocks/CU.
//   head0: Q * log2(e)/sqrt(128) -> Qs ; head1: K -> Kb ; head2: V -> Vt^T
// ---------------------------------------------------------------------------
__global__ __launch_bounds__(256) void qkv_kernel(
    const float* __restrict__ X, const unsigned short* __restrict__ Wb,
    unsigned short* __restrict__ Qs, unsigned short* __restrict__ Kb, unsigned short* __restrict__ Vt)
{
    __shared__ __align__(16) char lds[49152];   // X dbuf 2x8KB @0; W dbuf 2x16KB @16384
    const int tid  = threadIdx.x;
    const int lane = tid & 63, wid = tid >> 6;
    const int lrow = lane & 15, lgrp = lane >> 4;
    const int m0   = blockIdx.x * 64;
    const int hd   = blockIdx.y;
    const unsigned short* W = Wb + (size_t)hd * 131072;

    const char* wsrc[4];
    int wdoff[4];
#pragma unroll
    for (int g = 0; g < 4; ++g) {
        const int slot = g * 256 + tid;          // 0..1023
        const int row = slot >> 3, c16 = slot & 7;
        wsrc[g] = (const char*)(W + (size_t)row * 1024) + 16 * (c16 ^ (row & 7));
        wdoff[g] = g * 4096 + wid * 1024;
    }
    const int xrow = tid >> 2, xseg = tid & 3;   // 64 rows x 4 segs x 16 f32
    const float* xbase = X + (size_t)(m0 + xrow) * 1024 + xseg * 16;
    const int xsw = (xrow & 7) << 4;
    const int xwoff0 = xrow * 128 + (((xseg * 2)     * 16) ^ xsw);
    const int xwoff1 = xrow * 128 + (((xseg * 2 + 1) * 16) ^ xsw);

    f32x4 acc[8];
#pragma unroll
    for (int b = 0; b < 8; b++) acc[b] = (f32x4)0.0f;

#pragma unroll
    for (int g = 0; g < 4; ++g) GLOAD16(wsrc[g], lds + 16384 + wdoff[g]);
    {
        f32x4 x0 = *(const f32x4*)(xbase);
        f32x4 x1 = *(const f32x4*)(xbase + 4);
        f32x4 x2 = *(const f32x4*)(xbase + 8);
        f32x4 x3 = *(const f32x4*)(xbase + 12);
        *(short8*)(lds + xwoff0) = pack8(x0[0], x0[1], x0[2], x0[3], x1[0], x1[1], x1[2], x1[3]);
        *(short8*)(lds + xwoff1) = pack8(x2[0], x2[1], x2[2], x2[3], x3[0], x3[1], x3[2], x3[3]);
    }
    __syncthreads();

    for (int ks = 0; ks < 16; ++ks) {
        const int buf = ks & 1;
        f32x4 nx0, nx1, nx2, nx3;
        if (ks < 15) {
#pragma unroll
            for (int g = 0; g < 4; ++g)
                GLOAD16(wsrc[g] + (size_t)(ks + 1) * 128, lds + 16384 + (buf ^ 1) * 16384 + wdoff[g]);
            nx0 = *(const f32x4*)(xbase + (ks + 1) * 64);
            nx1 = *(const f32x4*)(xbase + (ks + 1) * 64 + 4);
            nx2 = *(const f32x4*)(xbase + (ks + 1) * 64 + 8);
            nx3 = *(const f32x4*)(xbase + (ks + 1) * 64 + 12);
        }
        const char* xb  = lds + buf * 8192;
        const char* wbl = lds + 16384 + buf * 16384;
        __builtin_amdgcn_s_setprio(1);
#pragma unroll
        for (int kc = 0; kc < 2; ++kc) {
            const int arow = wid * 16 + lrow;
            const int koff = (kc * 64 + lgrp * 16) ^ ((lrow & 7) << 4);
            short8 a = *(const short8*)(xb + arow * 128 + koff);
#pragma unroll
            for (int cf = 0; cf < 8; ++cf) {
                const int n = cf * 16 + lrow;
                short8 b = *(const short8*)(wbl + n * 128 + koff);
                acc[cf] = MFMA16(a, b, acc[cf]);
            }
        }
        __builtin_amdgcn_s_setprio(0);
        if (ks < 15) {
            *(short8*)(lds + (buf ^ 1) * 8192 + xwoff0) =
                pack8(nx0[0], nx0[1], nx0[2], nx0[3], nx1[0], nx1[1], nx1[2], nx1[3]);
            *(short8*)(lds + (buf ^ 1) * 8192 + xwoff1) =
                pack8(nx2[0], nx2[1], nx2[2], nx2[3], nx3[0], nx3[1], nx3[2], nx3[3]);
        }
        __syncthreads();
    }

    const float qscale = 0.12752039f;   // log2(e)/sqrt(128)
    if (hd < 2) {
        unsigned short* dst = (hd == 0) ? Qs : Kb;
        const float sc = (hd == 0) ? qscale : 1.0f;
#pragma unroll
        for (int cf = 0; cf < 8; ++cf)
#pragma unroll
            for (int r = 0; r < 4; ++r) {
                const int row = m0 + wid * 16 + lgrp * 4 + r;
                const int col = cf * 16 + lrow;
                dst[(size_t)row * 128 + col] = f2bf(acc[cf][r] * sc);
            }
    } else {
#pragma unroll
        for (int cf = 0; cf < 8; ++cf) {
            const int row0 = m0 + wid * 16 + lgrp * 4;
            const int col  = cf * 16 + lrow;
            ushort4_ v;
#pragma unroll
            for (int r = 0; r < 4; r++) v[r] = f2bf(acc[cf][r]);
            *(ushort4_*)(Vt + (size_t)col * 8192 + row0) = v;
        }
    }
}

// ---------------------------------------------------------------------------
// Kernel 2: flash-attention partial (r7 version — best measured, 65.8 us).
// KVBLK=64, 16 iters. grid 512 = 64 q-tiles(128 rows) x 8 kv-splits(1024;
// sp==blockIdx&7==XCD -> L2-private K/V slice). Block 256 = 4 waves x 32 q
// (j=0,1). K AND V staged via global_load_lds w16 into 64KB dbuf LDS
// (sigma-permuted / XOR-swizzled SOURCE, linear dest). 8 glds issued at iter
// top into buf^1, ONE __syncthreads per iter. 2 blocks/CU.
// ---------------------------------------------------------------------------
__global__ __launch_bounds__(256) void attn_kernel(
    const unsigned short* __restrict__ Qs,
    const unsigned short* __restrict__ Kb,
    const unsigned short* __restrict__ Vt,
    unsigned short* __restrict__ partO, float* __restrict__ partML)
{
    __shared__ __align__(16) char lds[65536];   // [buf][K 16KB | V 16KB]
    const int tid = threadIdx.x, lane = tid & 63, wid = tid >> 6;
    const int lrow = lane & 15, lgrp = lane >> 4;
    const int qtile = blockIdx.x >> 3, sp = blockIdx.x & 7;
    const int qb = qtile * 128 + wid * 32;
    const int kvstart = sp * 1024;

    // --- K staging: 4 glds/thread; 64 sigma-permuted rows, swizzled source ---
    const char* ksrc[4];
    int kdoff[4];
#pragma unroll
    for (int g = 0; g < 4; ++g) {
        const int slot = g * 16 + wid * 4 + lgrp;            // 0..63
        const int krow = (slot & 32) | (((slot >> 2) & 3) << 3)
                       | (((slot >> 4) & 1) << 2) | (slot & 3);
        ksrc[g] = (const char*)Kb + (size_t)(kvstart + krow) * 256
                + 16 * (lrow ^ (slot & 15));
        kdoff[g] = g * 4096 + wid * 1024;                    // + buf*32768
    }
    // --- V staging: 4 glds/thread; tile [128 d][128B], row-XOR swizzle ---
    const char* vsrc[4];
    int vdoff[4];
#pragma unroll
    for (int g = 0; g < 4; ++g) {
        const int drow = (wid * 4 + g) * 8 + (lane >> 3);    // 0..127
        vsrc[g] = (const char*)Vt + (size_t)drow * 16384 + (size_t)kvstart * 2
                + (((lane & 7) * 16) ^ ((drow & 7) << 4));
        vdoff[g] = (wid * 4 + g) * 1024;                     // + buf*32768 + 16384
    }

    // Q fragments: lane holds Q[qb + j*16 + lrow][c*32 + lgrp*8 ..]
    short8 qf[2][4];
#pragma unroll
    for (int j = 0; j < 2; ++j)
#pragma unroll
        for (int c = 0; c < 4; ++c)
            qf[j][c] = *(const short8*)(Qs + (size_t)(qb + j * 16 + lrow) * 128 + c * 32 + lgrp * 8);

    f32x4 o[2][8];
#pragma unroll
    for (int j = 0; j < 2; ++j)
#pragma unroll
        for (int i = 0; i < 8; ++i) o[j][i] = (f32x4)0.0f;
    float m[2] = { -1e30f, -1e30f }, l[2] = { 0.0f, 0.0f };

    // prologue: tile 0 -> buf 0
#pragma unroll
    for (int g = 0; g < 4; ++g) GLOAD16(ksrc[g], lds + kdoff[g]);
#pragma unroll
    for (int g = 0; g < 4; ++g) GLOAD16(vsrc[g], lds + 16384 + vdoff[g]);
    __syncthreads();

    for (int t = 0; t < 16; ++t) {
        const int buf = t & 1;
        const char* kb = lds + buf * 32768;
        const char* vb = kb + 16384;

        // ---- issue next tile's 8 glds into buf^1 (overlap this iter) ----
        if (t < 15) {
            char* nk = lds + (buf ^ 1) * 32768;
#pragma unroll
            for (int g = 0; g < 4; ++g)
                GLOAD16(ksrc[g] + (size_t)(t + 1) * 16384, nk + kdoff[g]);
#pragma unroll
            for (int g = 0; g < 4; ++g)
                GLOAD16(vsrc[g] + (size_t)(t + 1) * 128, nk + 16384 + vdoff[g]);
        }

        // ---- S^T = K Q over 64 kv (exp2 domain; scale folded into Q) ----
        f32x4 s[2][4];
#pragma unroll
        for (int f = 0; f < 4; ++f) { s[0][f] = (f32x4)0.0f; s[1][f] = (f32x4)0.0f; }
        __builtin_amdgcn_s_setprio(1);
#pragma unroll
        for (int f = 0; f < 4; ++f) {
            const int rbase = (f * 16 + lrow) * 256;
            const int swz = lrow << 4;
#pragma unroll
            for (int c = 0; c < 4; ++c) {
                short8 kf = *(const short8*)(kb + rbase + ((c * 64 + lgrp * 16) ^ swz));
                s[0][f] = MFMA16(kf, qf[0][c], s[0][f]);
                s[1][f] = MFMA16(kf, qf[1][c], s[1][f]);
            }
        }
        __builtin_amdgcn_s_setprio(0);

        // ---- online softmax: lane owns q=lane&15 (per j);
        //      kv = (f>>1)*32 + 8*lgrp + 4*(f&1) + r ----
        float tm[2];
#pragma unroll
        for (int j = 0; j < 2; ++j) {
            float a0 = fmaxf(fmaxf(s[j][0][0], s[j][0][1]), fmaxf(s[j][0][2], s[j][0][3]));
            float a1 = fmaxf(fmaxf(s[j][1][0], s[j][1][1]), fmaxf(s[j][1][2], s[j][1][3]));
            float a2 = fmaxf(fmaxf(s[j][2][0], s[j][2][1]), fmaxf(s[j][2][2], s[j][2][3]));
            float a3 = fmaxf(fmaxf(s[j][3][0], s[j][3][1]), fmaxf(s[j][3][2], s[j][3][3]));
            float t2 = fmaxf(fmaxf(a0, a1), fmaxf(a2, a3));
            t2 = fmaxf(t2, __shfl_xor(t2, 16));
            t2 = fmaxf(t2, __shfl_xor(t2, 32));
            tm[j] = t2;
        }
        const bool need = (tm[0] > m[0] + 8.0f) || (tm[1] > m[1] + 8.0f);
        if (__any(need)) {   // deferred-max rescale
#pragma unroll
            for (int j = 0; j < 2; ++j) {
                const float mn = fmaxf(m[j], tm[j]);
                const float al = exp2_fast(m[j] - mn);
                m[j] = mn;
                l[j] *= al;
#pragma unroll
                for (int r = 0; r < 4; ++r) {
                    const float ar = __shfl(al, lgrp * 4 + r);
#pragma unroll
                    for (int df = 0; df < 8; ++df) o[j][df][r] *= ar;
                }
            }
        }
        short8 pa[2][2];
#pragma unroll
        for (int j = 0; j < 2; ++j) {
            float rs = 0.0f;
#pragma unroll
            for (int f = 0; f < 4; ++f)
#pragma unroll
                for (int r = 0; r < 4; ++r) {
                    const float p = exp2_fast(s[j][f][r] - m[j]);
                    s[j][f][r] = p;
                    rs += p;
                }
            rs += __shfl_xor(rs, 16);
            rs += __shfl_xor(rs, 32);
            l[j] += rs;
            pa[j][0] = pack8(s[j][0][0], s[j][0][1], s[j][0][2], s[j][0][3],
                             s[j][1][0], s[j][1][1], s[j][1][2], s[j][1][3]);
            pa[j][1] = pack8(s[j][2][0], s[j][2][1], s[j][2][2], s[j][2][3],
                             s[j][3][0], s[j][3][1], s[j][3][2], s[j][3][3]);
        }

        // ---- O += P V (V from LDS; 16 reads, 32 MFMA) ----
        __builtin_amdgcn_s_setprio(1);
#pragma unroll
        for (int ks = 0; ks < 2; ++ks) {
#pragma unroll
            for (int df = 0; df < 8; ++df) {
                const int d = df * 16 + lrow;
                short8 vf = *(const short8*)(vb + d * 128 +
                              ((ks * 64 + lgrp * 16) ^ ((d & 7) << 4)));
                o[0][df] = MFMA16(pa[0][ks], vf, o[0][df]);
                o[1][df] = MFMA16(pa[1][ks], vf, o[1][df]);
            }
        }
        __builtin_amdgcn_s_setprio(0);

        __syncthreads();   // drains this wave's glds; orders buf swap
    }

    // ---- state to row form (row = j*16 + lgrp*4 + r) ----
    float mr[2][4], lr_[2][4];
#pragma unroll
    for (int j = 0; j < 2; ++j)
#pragma unroll
        for (int r = 0; r < 4; ++r) {
            mr[j][r]  = __shfl(m[j], lgrp * 4 + r);
            lr_[j][r] = __shfl(l[j], lgrp * 4 + r);
        }

    // ---- write bf16 unnormalized partial + f32 (m,l) ----
#pragma unroll
    for (int j = 0; j < 2; ++j)
#pragma unroll
        for (int df = 0; df < 8; ++df)
#pragma unroll
            for (int r = 0; r < 4; ++r) {
                const int qg = qb + j * 16 + lgrp * 4 + r;
                partO[((size_t)sp * 8192 + qg) * 128 + df * 16 + lrow] = f2bf(o[j][df][r]);
            }
    if (lrow == 0) {
#pragma unroll
        for (int j = 0; j < 2; ++j)
#pragma unroll
            for (int r = 0; r < 4; ++r) {
                const int qg = qb + j * 16 + lgrp * 4 + r;
                partML[((size_t)sp * 8192 + qg) * 2]     = mr[j][r];
                partML[((size_t)sp * 8192 + qg) * 2 + 1] = lr_[j][r];
            }
    }
}

// ---------------------------------------------------------------------------
// Kernel 3: merge 8 kv-split bf16 partials and normalize.
// ---------------------------------------------------------------------------
__global__ __launch_bounds__(256) void merge_kernel(
    const unsigned short* __restrict__ partO, const float* __restrict__ partML,
    float* __restrict__ out)
{
    const int gid = blockIdx.x * 256 + threadIdx.x;   // 0..262143
    const int q = gid >> 5, dc = gid & 31;
    float mv[8], lv[8];
#pragma unroll
    for (int spv = 0; spv < 8; ++spv) {
        mv[spv] = partML[((size_t)spv * 8192 + q) * 2];
        lv[spv] = partML[((size_t)spv * 8192 + q) * 2 + 1];
    }
    float M = mv[0];
#pragma unroll
    for (int spv = 1; spv < 8; ++spv) M = fmaxf(M, mv[spv]);
    float e[8], L = 0.f;
#pragma unroll
    for (int spv = 0; spv < 8; ++spv) { e[spv] = exp2_fast(mv[spv] - M); L += lv[spv] * e[spv]; }
    const float inv = 1.0f / L;
    f32x4 r = (f32x4)0.0f;
#pragma unroll
    for (int spv = 0; spv < 8; ++spv) {
        ushort4_ v = *(const ushort4_*)(partO + ((size_t)spv * 8192 + q) * 128 + dc * 4);
#pragma unroll
        for (int k = 0; k < 4; ++k) r[k] += bf2f(v[k]) * e[spv];
    }
#pragma unroll
    for (int k = 0; k < 4; ++k) r[k] *= inv;
    *(f32x4*)(out + (size_t)q * 128 + dc * 4) = r;
}

extern "C" void kernel_launch(void* const* d_in, const int* in_sizes, int n_in,
                              void* d_out, int out_size, void* d_ws, size_t ws_size,
                              hipStream_t stream)
{
    const float* X  = (const float*)d_in[0];
    const float* Wq = (const float*)d_in[1];
    const float* Wk = (const float*)d_in[2];
    const float* Wv = (const float*)d_in[3];

    char* ws = (char*)d_ws;
    const size_t QS_OFF  = 0;                                   // 2 MiB
    const size_t KB_OFF  = QS_OFF + (size_t)8192 * 128 * 2;     // 2 MiB
    const size_t VT_OFF  = KB_OFF + (size_t)8192 * 128 * 2;     // 2 MiB (V transposed)
    const size_t WB_OFF  = VT_OFF + (size_t)8192 * 128 * 2;     // 768 KiB
    const size_t PO_OFF  = WB_OFF + (size_t)3 * 128 * 1024 * 2; // 8*8192*128 bf16 = 16 MiB
    const size_t PML_OFF = PO_OFF + (size_t)8 * 8192 * 128 * 2; // 8*8192*2 f32 = 512 KiB

    unsigned short* Qs  = (unsigned short*)(ws + QS_OFF);
    unsigned short* Kb  = (unsigned short*)(ws + KB_OFF);
    unsigned short* Vt  = (unsigned short*)(ws + VT_OFF);
    unsigned short* Wb  = (unsigned short*)(ws + WB_OFF);
    unsigned short* partO = (unsigned short*)(ws + PO_OFF);
    float* partML = (float*)(ws + PML_OFF);
    float* out = (float*)d_out;

    wcvt_kernel<<<dim3(128, 3), 256, 0, stream>>>(Wq, Wk, Wv, Wb);
    qkv_kernel<<<dim3(128, 3), 256, 0, stream>>>(X, Wb, Qs, Kb, Vt);
    attn_kernel<<<dim3(512), 256, 0, stream>>>(Qs, Kb, Vt, partO, partML);
    merge_kernel<<<dim3(1024), 256, 0, stream>>>(partO, partML, out);
}

// Round 12
// 72.977 us; speedup vs baseline: 2.2200x; 1.2189x over previous
//
#include <hip/hip_runtime.h>
#include <stdint.h>

typedef __attribute__((ext_vector_type(8))) short short8;       // 8 x bf16
typedef __attribute__((ext_vector_type(4))) float f32x4;
typedef __attribute__((ext_vector_type(4))) unsigned short ushort4_;
typedef __attribute__((ext_vector_type(4))) unsigned int uint4_;

#define MFMA16(a, b, c) __builtin_amdgcn_mfma_f32_16x16x32_bf16((a), (b), (c), 0, 0, 0)

static __device__ __forceinline__ unsigned short f2bf(float f) {
    unsigned u = __float_as_uint(f);
    u += 0x7fffu + ((u >> 16) & 1u);   // RNE
    return (unsigned short)(u >> 16);
}

static __device__ __forceinline__ float bf2f(unsigned short u) {
    return __uint_as_float(((unsigned)u) << 16);
}

static __device__ __forceinline__ float exp2_fast(float x) {
#if __has_builtin(__builtin_amdgcn_exp2f)
    return __builtin_amdgcn_exp2f(x);
#else
    return exp2f(x);
#endif
}

static __device__ __forceinline__ unsigned cvt_pk(float lo, float hi) {
    unsigned r;
    asm("v_cvt_pk_bf16_f32 %0, %1, %2" : "=v"(r) : "v"(lo), "v"(hi));
    return r;
}

static __device__ __forceinline__ short8 pack8(float a0, float a1, float a2, float a3,
                                               float a4, float a5, float a6, float a7) {
    union { uint4_ u; short8 s; } c;
    c.u[0] = cvt_pk(a0, a1); c.u[1] = cvt_pk(a2, a3);
    c.u[2] = cvt_pk(a4, a5); c.u[3] = cvt_pk(a6, a7);
    return c.s;
}

#define GLOAD16(SRC, DSTPTR) __builtin_amdgcn_global_load_lds(                       \
    (const __attribute__((address_space(1))) void*)(SRC),                            \
    (__attribute__((address_space(3))) void*)(DSTPTR), 16, 0, 0)

// ---------------------------------------------------------------------------
// Kernel 0: W (3 heads, f32) -> bf16, contiguous Wb[3][128][1024]
// ---------------------------------------------------------------------------
__global__ __launch_bounds__(256) void wcvt_kernel(
    const float* __restrict__ Wq, const float* __restrict__ Wk, const float* __restrict__ Wv,
    unsigned short* __restrict__ Wb)
{
    const int hd = blockIdx.y;
    const float* W = (hd == 0) ? Wq : ((hd == 1) ? Wk : Wv);
    const int idx = (blockIdx.x * 256 + threadIdx.x) * 4;
    f32x4 v = *(const f32x4*)(W + idx);
    ushort4_ o;
#pragma unroll
    for (int j = 0; j < 4; ++j) o[j] = f2bf(v[j]);
    *(ushort4_*)(Wb + (size_t)hd * 131072 + idx) = o;
}

// ---------------------------------------------------------------------------
// Kernel 1: QKV projection (r9 version — best measured).
// Per-head blocks: grid (128, 3), M-tile 64, 4 waves x 16 rows. K-step 64,
// 16 steps, ONE __syncthreads per step. W via global_load_lds w16 (swizzled
// source); X f32 reg-staged (T14). LDS 48KB -> 3 blocks/CU.
//   head0: Q * log2(e)/sqrt(128) -> Qs ; head1: K -> Kb ; head2: V -> Vt^T
// ---------------------------------------------------------------------------
__global__ __launch_bounds__(256) void qkv_kernel(
    const float* __restrict__ X, const unsigned short* __restrict__ Wb,
    unsigned short* __restrict__ Qs, unsigned short* __restrict__ Kb, unsigned short* __restrict__ Vt)
{
    __shared__ __align__(16) char lds[49152];   // X dbuf 2x8KB @0; W dbuf 2x16KB @16384
    const int tid  = threadIdx.x;
    const int lane = tid & 63, wid = tid >> 6;
    const int lrow = lane & 15, lgrp = lane >> 4;
    const int m0   = blockIdx.x * 64;
    const int hd   = blockIdx.y;
    const unsigned short* W = Wb + (size_t)hd * 131072;

    const char* wsrc[4];
    int wdoff[4];
#pragma unroll
    for (int g = 0; g < 4; ++g) {
        const int slot = g * 256 + tid;          // 0..1023
        const int row = slot >> 3, c16 = slot & 7;
        wsrc[g] = (const char*)(W + (size_t)row * 1024) + 16 * (c16 ^ (row & 7));
        wdoff[g] = g * 4096 + wid * 1024;
    }
    const int xrow = tid >> 2, xseg = tid & 3;   // 64 rows x 4 segs x 16 f32
    const float* xbase = X + (size_t)(m0 + xrow) * 1024 + xseg * 16;
    const int xsw = (xrow & 7) << 4;
    const int xwoff0 = xrow * 128 + (((xseg * 2)     * 16) ^ xsw);
    const int xwoff1 = xrow * 128 + (((xseg * 2 + 1) * 16) ^ xsw);

    f32x4 acc[8];
#pragma unroll
    for (int b = 0; b < 8; b++) acc[b] = (f32x4)0.0f;

#pragma unroll
    for (int g = 0; g < 4; ++g) GLOAD16(wsrc[g], lds + 16384 + wdoff[g]);
    {
        f32x4 x0 = *(const f32x4*)(xbase);
        f32x4 x1 = *(const f32x4*)(xbase + 4);
        f32x4 x2 = *(const f32x4*)(xbase + 8);
        f32x4 x3 = *(const f32x4*)(xbase + 12);
        *(short8*)(lds + xwoff0) = pack8(x0[0], x0[1], x0[2], x0[3], x1[0], x1[1], x1[2], x1[3]);
        *(short8*)(lds + xwoff1) = pack8(x2[0], x2[1], x2[2], x2[3], x3[0], x3[1], x3[2], x3[3]);
    }
    __syncthreads();

    for (int ks = 0; ks < 16; ++ks) {
        const int buf = ks & 1;
        f32x4 nx0, nx1, nx2, nx3;
        if (ks < 15) {
#pragma unroll
            for (int g = 0; g < 4; ++g)
                GLOAD16(wsrc[g] + (size_t)(ks + 1) * 128, lds + 16384 + (buf ^ 1) * 16384 + wdoff[g]);
            nx0 = *(const f32x4*)(xbase + (ks + 1) * 64);
            nx1 = *(const f32x4*)(xbase + (ks + 1) * 64 + 4);
            nx2 = *(const f32x4*)(xbase + (ks + 1) * 64 + 8);
            nx3 = *(const f32x4*)(xbase + (ks + 1) * 64 + 12);
        }
        const char* xb  = lds + buf * 8192;
        const char* wbl = lds + 16384 + buf * 16384;
        __builtin_amdgcn_s_setprio(1);
#pragma unroll
        for (int kc = 0; kc < 2; ++kc) {
            const int arow = wid * 16 + lrow;
            const int koff = (kc * 64 + lgrp * 16) ^ ((lrow & 7) << 4);
            short8 a = *(const short8*)(xb + arow * 128 + koff);
#pragma unroll
            for (int cf = 0; cf < 8; ++cf) {
                const int n = cf * 16 + lrow;
                short8 b = *(const short8*)(wbl + n * 128 + koff);
                acc[cf] = MFMA16(a, b, acc[cf]);
            }
        }
        __builtin_amdgcn_s_setprio(0);
        if (ks < 15) {
            *(short8*)(lds + (buf ^ 1) * 8192 + xwoff0) =
                pack8(nx0[0], nx0[1], nx0[2], nx0[3], nx1[0], nx1[1], nx1[2], nx1[3]);
            *(short8*)(lds + (buf ^ 1) * 8192 + xwoff1) =
                pack8(nx2[0], nx2[1], nx2[2], nx2[3], nx3[0], nx3[1], nx3[2], nx3[3]);
        }
        __syncthreads();
    }

    const float qscale = 0.12752039f;   // log2(e)/sqrt(128)
    if (hd < 2) {
        unsigned short* dst = (hd == 0) ? Qs : Kb;
        const float sc = (hd == 0) ? qscale : 1.0f;
#pragma unroll
        for (int cf = 0; cf < 8; ++cf)
#pragma unroll
            for (int r = 0; r < 4; ++r) {
                const int row = m0 + wid * 16 + lgrp * 4 + r;
                const int col = cf * 16 + lrow;
                dst[(size_t)row * 128 + col] = f2bf(acc[cf][r] * sc);
            }
    } else {
#pragma unroll
        for (int cf = 0; cf < 8; ++cf) {
            const int row0 = m0 + wid * 16 + lgrp * 4;
            const int col  = cf * 16 + lrow;
            ushort4_ v;
#pragma unroll
            for (int r = 0; r < 4; r++) v[r] = f2bf(acc[cf][r]);
            *(ushort4_*)(Vt + (size_t)col * 8192 + row0) = v;
        }
    }
}

// ---------------------------------------------------------------------------
// Kernel 2: flash-attention partial — r7/r11 schedule widened to 8 waves.
// Block 512 = 8 waves x 32 q (j=0,1); q-tile 256 rows. grid 256 = 32 q-tiles
// x 8 kv-splits (sp==XCD). KVBLK=64, 16 iters. K AND V staged via
// global_load_lds w16 into 64KB dbuf LDS (sigma-permuted / XOR-swizzled
// SOURCE, linear dest); 2 K-glds + 2 V-glds per thread. 1 block/CU;
// per-CU-iter staging traffic HALVES vs r11 (same MFMA work).
// ---------------------------------------------------------------------------
__global__ __launch_bounds__(512) void attn_kernel(
    const unsigned short* __restrict__ Qs,
    const unsigned short* __restrict__ Kb,
    const unsigned short* __restrict__ Vt,
    unsigned short* __restrict__ partO, float* __restrict__ partML)
{
    __shared__ __align__(16) char lds[65536];   // [buf][K 16KB | V 16KB]
    const int tid = threadIdx.x, lane = tid & 63, wid = tid >> 6;   // wid 0..7
    const int lrow = lane & 15, lgrp = lane >> 4;
    const int qtile = blockIdx.x >> 3, sp = blockIdx.x & 7;
    const int qb = qtile * 256 + wid * 32;
    const int kvstart = sp * 1024;

    // --- K staging: 2 glds/thread; 64 sigma-permuted rows, swizzled source ---
    const char* ksrc[2];
    int kdoff[2];
#pragma unroll
    for (int g = 0; g < 2; ++g) {
        const int slot = g * 32 + wid * 4 + lgrp;            // 0..63 bijective
        const int krow = (slot & 32) | (((slot >> 2) & 3) << 3)
                       | (((slot >> 4) & 1) << 2) | (slot & 3);
        ksrc[g] = (const char*)Kb + (size_t)(kvstart + krow) * 256
                + 16 * (lrow ^ (slot & 15));
        kdoff[g] = g * 8192 + wid * 1024;                    // + buf*32768
    }
    // --- V staging: 2 glds/thread; tile [128 d][128B], row-XOR swizzle ---
    const char* vsrc[2];
    int vdoff[2];
#pragma unroll
    for (int g = 0; g < 2; ++g) {
        const int drow = (wid * 2 + g) * 8 + (lane >> 3);    // 0..127 bijective
        vsrc[g] = (const char*)Vt + (size_t)drow * 16384 + (size_t)kvstart * 2
                + (((lane & 7) * 16) ^ ((drow & 7) << 4));
        vdoff[g] = (wid * 2 + g) * 1024;                     // + buf*32768 + 16384
    }

    // Q fragments: lane holds Q[qb + j*16 + lrow][c*32 + lgrp*8 ..]
    short8 qf[2][4];
#pragma unroll
    for (int j = 0; j < 2; ++j)
#pragma unroll
        for (int c = 0; c < 4; ++c)
            qf[j][c] = *(const short8*)(Qs + (size_t)(qb + j * 16 + lrow) * 128 + c * 32 + lgrp * 8);

    f32x4 o[2][8];
#pragma unroll
    for (int j = 0; j < 2; ++j)
#pragma unroll
        for (int i = 0; i < 8; ++i) o[j][i] = (f32x4)0.0f;
    float m[2] = { -1e30f, -1e30f }, l[2] = { 0.0f, 0.0f };

    // prologue: tile 0 -> buf 0
#pragma unroll
    for (int g = 0; g < 2; ++g) GLOAD16(ksrc[g], lds + kdoff[g]);
#pragma unroll
    for (int g = 0; g < 2; ++g) GLOAD16(vsrc[g], lds + 16384 + vdoff[g]);
    __syncthreads();

    for (int t = 0; t < 16; ++t) {
        const int buf = t & 1;
        const char* kb = lds + buf * 32768;
        const char* vb = kb + 16384;

        // ---- issue next tile's 4 glds into buf^1 (fly through this iter) ----
        if (t < 15) {
            char* nk = lds + (buf ^ 1) * 32768;
#pragma unroll
            for (int g = 0; g < 2; ++g)
                GLOAD16(ksrc[g] + (size_t)(t + 1) * 16384, nk + kdoff[g]);
#pragma unroll
            for (int g = 0; g < 2; ++g)
                GLOAD16(vsrc[g] + (size_t)(t + 1) * 128, nk + 16384 + vdoff[g]);
        }

        // ---- S^T = K Q over 64 kv (exp2 domain; scale folded into Q) ----
        f32x4 s[2][4];
#pragma unroll
        for (int f = 0; f < 4; ++f) { s[0][f] = (f32x4)0.0f; s[1][f] = (f32x4)0.0f; }
        __builtin_amdgcn_s_setprio(1);
#pragma unroll
        for (int f = 0; f < 4; ++f) {
            const int rbase = (f * 16 + lrow) * 256;
            const int swz = lrow << 4;
#pragma unroll
            for (int c = 0; c < 4; ++c) {
                short8 kf = *(const short8*)(kb + rbase + ((c * 64 + lgrp * 16) ^ swz));
                s[0][f] = MFMA16(kf, qf[0][c], s[0][f]);
                s[1][f] = MFMA16(kf, qf[1][c], s[1][f]);
            }
        }
        __builtin_amdgcn_s_setprio(0);

        // ---- online softmax: lane owns q=lane&15 (per j);
        //      kv = (f>>1)*32 + 8*lgrp + 4*(f&1) + r ----
        float tm[2];
#pragma unroll
        for (int j = 0; j < 2; ++j) {
            float a0 = fmaxf(fmaxf(s[j][0][0], s[j][0][1]), fmaxf(s[j][0][2], s[j][0][3]));
            float a1 = fmaxf(fmaxf(s[j][1][0], s[j][1][1]), fmaxf(s[j][1][2], s[j][1][3]));
            float a2 = fmaxf(fmaxf(s[j][2][0], s[j][2][1]), fmaxf(s[j][2][2], s[j][2][3]));
            float a3 = fmaxf(fmaxf(s[j][3][0], s[j][3][1]), fmaxf(s[j][3][2], s[j][3][3]));
            float t2 = fmaxf(fmaxf(a0, a1), fmaxf(a2, a3));
            t2 = fmaxf(t2, __shfl_xor(t2, 16));
            t2 = fmaxf(t2, __shfl_xor(t2, 32));
            tm[j] = t2;
        }
        const bool need = (tm[0] > m[0] + 8.0f) || (tm[1] > m[1] + 8.0f);
        if (__any(need)) {   // deferred-max rescale
#pragma unroll
            for (int j = 0; j < 2; ++j) {
                const float mn = fmaxf(m[j], tm[j]);
                const float al = exp2_fast(m[j] - mn);
                m[j] = mn;
                l[j] *= al;
#pragma unroll
                for (int r = 0; r < 4; ++r) {
                    const float ar = __shfl(al, lgrp * 4 + r);
#pragma unroll
                    for (int df = 0; df < 8; ++df) o[j][df][r] *= ar;
                }
            }
        }
        short8 pa[2][2];
#pragma unroll
        for (int j = 0; j < 2; ++j) {
            float rs = 0.0f;
#pragma unroll
            for (int f = 0; f < 4; ++f)
#pragma unroll
                for (int r = 0; r < 4; ++r) {
                    const float p = exp2_fast(s[j][f][r] - m[j]);
                    s[j][f][r] = p;
                    rs += p;
                }
            rs += __shfl_xor(rs, 16);
            rs += __shfl_xor(rs, 32);
            l[j] += rs;
            pa[j][0] = pack8(s[j][0][0], s[j][0][1], s[j][0][2], s[j][0][3],
                             s[j][1][0], s[j][1][1], s[j][1][2], s[j][1][3]);
            pa[j][1] = pack8(s[j][2][0], s[j][2][1], s[j][2][2], s[j][2][3],
                             s[j][3][0], s[j][3][1], s[j][3][2], s[j][3][3]);
        }

        // ---- O += P V (V from LDS; 16 reads, 32 MFMA) ----
        __builtin_amdgcn_s_setprio(1);
#pragma unroll
        for (int ks = 0; ks < 2; ++ks) {
#pragma unroll
            for (int df = 0; df < 8; ++df) {
                const int d = df * 16 + lrow;
                short8 vf = *(const short8*)(vb + d * 128 +
                              ((ks * 64 + lgrp * 16) ^ ((d & 7) << 4)));
                o[0][df] = MFMA16(pa[0][ks], vf, o[0][df]);
                o[1][df] = MFMA16(pa[1][ks], vf, o[1][df]);
            }
        }
        __builtin_amdgcn_s_setprio(0);

        __syncthreads();   // drains this iter's glds; orders buf swap
    }

    // ---- state to row form (row = j*16 + lgrp*4 + r) ----
    float mr[2][4], lr_[2][4];
#pragma unroll
    for (int j = 0; j < 2; ++j)
#pragma unroll
        for (int r = 0; r < 4; ++r) {
            mr[j][r]  = __shfl(m[j], lgrp * 4 + r);
            lr_[j][r] = __shfl(l[j], lgrp * 4 + r);
        }

    // ---- write bf16 unnormalized partial + f32 (m,l) ----
#pragma unroll
    for (int j = 0; j < 2; ++j)
#pragma unroll
        for (int df = 0; df < 8; ++df)
#pragma unroll
            for (int r = 0; r < 4; ++r) {
                const int qg = qb + j * 16 + lgrp * 4 + r;
                partO[((size_t)sp * 8192 + qg) * 128 + df * 16 + lrow] = f2bf(o[j][df][r]);
            }
    if (lrow == 0) {
#pragma unroll
        for (int j = 0; j < 2; ++j)
#pragma unroll
            for (int r = 0; r < 4; ++r) {
                const int qg = qb + j * 16 + lgrp * 4 + r;
                partML[((size_t)sp * 8192 + qg) * 2]     = mr[j][r];
                partML[((size_t)sp * 8192 + qg) * 2 + 1] = lr_[j][r];
            }
    }
}

// ---------------------------------------------------------------------------
// Kernel 3: merge 8 kv-split bf16 partials and normalize.
// ---------------------------------------------------------------------------
__global__ __launch_bounds__(256) void merge_kernel(
    const unsigned short* __restrict__ partO, const float* __restrict__ partML,
    float* __restrict__ out)
{
    const int gid = blockIdx.x * 256 + threadIdx.x;   // 0..262143
    const int q = gid >> 5, dc = gid & 31;
    float mv[8], lv[8];
#pragma unroll
    for (int spv = 0; spv < 8; ++spv) {
        mv[spv] = partML[((size_t)spv * 8192 + q) * 2];
        lv[spv] = partML[((size_t)spv * 8192 + q) * 2 + 1];
    }
    float M = mv[0];
#pragma unroll
    for (int spv = 1; spv < 8; ++spv) M = fmaxf(M, mv[spv]);
    float e[8], L = 0.f;
#pragma unroll
    for (int spv = 0; spv < 8; ++spv) { e[spv] = exp2_fast(mv[spv] - M); L += lv[spv] * e[spv]; }
    const float inv = 1.0f / L;
    f32x4 r = (f32x4)0.0f;
#pragma unroll
    for (int spv = 0; spv < 8; ++spv) {
        ushort4_ v = *(const ushort4_*)(partO + ((size_t)spv * 8192 + q) * 128 + dc * 4);
#pragma unroll
        for (int k = 0; k < 4; ++k) r[k] += bf2f(v[k]) * e[spv];
    }
#pragma unroll
    for (int k = 0; k < 4; ++k) r[k] *= inv;
    *(f32x4*)(out + (size_t)q * 128 + dc * 4) = r;
}

extern "C" void kernel_launch(void* const* d_in, const int* in_sizes, int n_in,
                              void* d_out, int out_size, void* d_ws, size_t ws_size,
                              hipStream_t stream)
{
    const float* X  = (const float*)d_in[0];
    const float* Wq = (const float*)d_in[1];
    const float* Wk = (const float*)d_in[2];
    const float* Wv = (const float*)d_in[3];

    char* ws = (char*)d_ws;
    const size_t QS_OFF  = 0;                                   // 2 MiB
    const size_t KB_OFF  = QS_OFF + (size_t)8192 * 128 * 2;     // 2 MiB
    const size_t VT_OFF  = KB_OFF + (size_t)8192 * 128 * 2;     // 2 MiB (V transposed)
    const size_t WB_OFF  = VT_OFF + (size_t)8192 * 128 * 2;     // 768 KiB
    const size_t PO_OFF  = WB_OFF + (size_t)3 * 128 * 1024 * 2; // 8*8192*128 bf16 = 16 MiB
    const size_t PML_OFF = PO_OFF + (size_t)8 * 8192 * 128 * 2; // 8*8192*2 f32 = 512 KiB

    unsigned short* Qs  = (unsigned short*)(ws + QS_OFF);
    unsigned short* Kb  = (unsigned short*)(ws + KB_OFF);
    unsigned short* Vt  = (unsigned short*)(ws + VT_OFF);
    unsigned short* Wb  = (unsigned short*)(ws + WB_OFF);
    unsigned short* partO = (unsigned short*)(ws + PO_OFF);
    float* partML = (float*)(ws + PML_OFF);
    float* out = (float*)d_out;

    wcvt_kernel<<<dim3(128, 3), 256, 0, stream>>>(Wq, Wk, Wv, Wb);
    qkv_kernel<<<dim3(128, 3), 256, 0, stream>>>(X, Wb, Qs, Kb, Vt);
    attn_kernel<<<dim3(256), 512, 0, stream>>>(Qs, Kb, Vt, partO, partML);
    merge_kernel<<<dim3(1024), 256, 0, stream>>>(partO, partML, out);
}

// Round 13
// 71.571 us; speedup vs baseline: 2.2636x; 1.0196x over previous
//
#include <hip/hip_runtime.h>
#include <stdint.h>

typedef __attribute__((ext_vector_type(8))) short short8;       // 8 x bf16
typedef __attribute__((ext_vector_type(4))) float f32x4;
typedef __attribute__((ext_vector_type(4))) unsigned short ushort4_;
typedef __attribute__((ext_vector_type(4))) unsigned int uint4_;

#define MFMA16(a, b, c) __builtin_amdgcn_mfma_f32_16x16x32_bf16((a), (b), (c), 0, 0, 0)

static __device__ __forceinline__ unsigned short f2bf(float f) {
    unsigned u = __float_as_uint(f);
    u += 0x7fffu + ((u >> 16) & 1u);   // RNE
    return (unsigned short)(u >> 16);
}

static __device__ __forceinline__ float bf2f(unsigned short u) {
    return __uint_as_float(((unsigned)u) << 16);
}

static __device__ __forceinline__ float exp2_fast(float x) {
#if __has_builtin(__builtin_amdgcn_exp2f)
    return __builtin_amdgcn_exp2f(x);
#else
    return exp2f(x);
#endif
}

static __device__ __forceinline__ unsigned cvt_pk(float lo, float hi) {
    unsigned r;
    asm("v_cvt_pk_bf16_f32 %0, %1, %2" : "=v"(r) : "v"(lo), "v"(hi));
    return r;
}

static __device__ __forceinline__ short8 pack8(float a0, float a1, float a2, float a3,
                                               float a4, float a5, float a6, float a7) {
    union { uint4_ u; short8 s; } c;
    c.u[0] = cvt_pk(a0, a1); c.u[1] = cvt_pk(a2, a3);
    c.u[2] = cvt_pk(a4, a5); c.u[3] = cvt_pk(a6, a7);
    return c.s;
}

#define GLOAD16(SRC, DSTPTR) __builtin_amdgcn_global_load_lds(                       \
    (const __attribute__((address_space(1))) void*)(SRC),                            \
    (__attribute__((address_space(3))) void*)(DSTPTR), 16, 0, 0)

// ---------------------------------------------------------------------------
// Kernel 0: W (3 heads, f32) -> bf16, contiguous Wb[3][128][1024]
// ---------------------------------------------------------------------------
__global__ __launch_bounds__(256) void wcvt_kernel(
    const float* __restrict__ Wq, const float* __restrict__ Wk, const float* __restrict__ Wv,
    unsigned short* __restrict__ Wb)
{
    const int hd = blockIdx.y;
    const float* W = (hd == 0) ? Wq : ((hd == 1) ? Wk : Wv);
    const int idx = (blockIdx.x * 256 + threadIdx.x) * 4;
    f32x4 v = *(const f32x4*)(W + idx);
    ushort4_ o;
#pragma unroll
    for (int j = 0; j < 4; ++j) o[j] = f2bf(v[j]);
    *(ushort4_*)(Wb + (size_t)hd * 131072 + idx) = o;
}

// ---------------------------------------------------------------------------
// Kernel 1: QKV projection (r9 version — best measured).
// Per-head blocks: grid (128, 3), M-tile 64, 4 waves x 16 rows. K-step 64,
// 16 steps, ONE __syncthreads per step. W via global_load_lds w16 (swizzled
// source); X f32 reg-staged (T14). LDS 48KB -> 3 blocks/CU.
//   head0: Q * log2(e)/sqrt(128) -> Qs ; head1: K -> Kb ; head2: V -> Vt^T
// ---------------------------------------------------------------------------
__global__ __launch_bounds__(256) void qkv_kernel(
    const float* __restrict__ X, const unsigned short* __restrict__ Wb,
    unsigned short* __restrict__ Qs, unsigned short* __restrict__ Kb, unsigned short* __restrict__ Vt)
{
    __shared__ __align__(16) char lds[49152];   // X dbuf 2x8KB @0; W dbuf 2x16KB @16384
    const int tid  = threadIdx.x;
    const int lane = tid & 63, wid = tid >> 6;
    const int lrow = lane & 15, lgrp = lane >> 4;
    const int m0   = blockIdx.x * 64;
    const int hd   = blockIdx.y;
    const unsigned short* W = Wb + (size_t)hd * 131072;

    const char* wsrc[4];
    int wdoff[4];
#pragma unroll
    for (int g = 0; g < 4; ++g) {
        const int slot = g * 256 + tid;          // 0..1023
        const int row = slot >> 3, c16 = slot & 7;
        wsrc[g] = (const char*)(W + (size_t)row * 1024) + 16 * (c16 ^ (row & 7));
        wdoff[g] = g * 4096 + wid * 1024;
    }
    const int xrow = tid >> 2, xseg = tid & 3;   // 64 rows x 4 segs x 16 f32
    const float* xbase = X + (size_t)(m0 + xrow) * 1024 + xseg * 16;
    const int xsw = (xrow & 7) << 4;
    const int xwoff0 = xrow * 128 + (((xseg * 2)     * 16) ^ xsw);
    const int xwoff1 = xrow * 128 + (((xseg * 2 + 1) * 16) ^ xsw);

    f32x4 acc[8];
#pragma unroll
    for (int b = 0; b < 8; b++) acc[b] = (f32x4)0.0f;

#pragma unroll
    for (int g = 0; g < 4; ++g) GLOAD16(wsrc[g], lds + 16384 + wdoff[g]);
    {
        f32x4 x0 = *(const f32x4*)(xbase);
        f32x4 x1 = *(const f32x4*)(xbase + 4);
        f32x4 x2 = *(const f32x4*)(xbase + 8);
        f32x4 x3 = *(const f32x4*)(xbase + 12);
        *(short8*)(lds + xwoff0) = pack8(x0[0], x0[1], x0[2], x0[3], x1[0], x1[1], x1[2], x1[3]);
        *(short8*)(lds + xwoff1) = pack8(x2[0], x2[1], x2[2], x2[3], x3[0], x3[1], x3[2], x3[3]);
    }
    __syncthreads();

    for (int ks = 0; ks < 16; ++ks) {
        const int buf = ks & 1;
        f32x4 nx0, nx1, nx2, nx3;
        if (ks < 15) {
#pragma unroll
            for (int g = 0; g < 4; ++g)
                GLOAD16(wsrc[g] + (size_t)(ks + 1) * 128, lds + 16384 + (buf ^ 1) * 16384 + wdoff[g]);
            nx0 = *(const f32x4*)(xbase + (ks + 1) * 64);
            nx1 = *(const f32x4*)(xbase + (ks + 1) * 64 + 4);
            nx2 = *(const f32x4*)(xbase + (ks + 1) * 64 + 8);
            nx3 = *(const f32x4*)(xbase + (ks + 1) * 64 + 12);
        }
        const char* xb  = lds + buf * 8192;
        const char* wbl = lds + 16384 + buf * 16384;
        __builtin_amdgcn_s_setprio(1);
#pragma unroll
        for (int kc = 0; kc < 2; ++kc) {
            const int arow = wid * 16 + lrow;
            const int koff = (kc * 64 + lgrp * 16) ^ ((lrow & 7) << 4);
            short8 a = *(const short8*)(xb + arow * 128 + koff);
#pragma unroll
            for (int cf = 0; cf < 8; ++cf) {
                const int n = cf * 16 + lrow;
                short8 b = *(const short8*)(wbl + n * 128 + koff);
                acc[cf] = MFMA16(a, b, acc[cf]);
            }
        }
        __builtin_amdgcn_s_setprio(0);
        if (ks < 15) {
            *(short8*)(lds + (buf ^ 1) * 8192 + xwoff0) =
                pack8(nx0[0], nx0[1], nx0[2], nx0[3], nx1[0], nx1[1], nx1[2], nx1[3]);
            *(short8*)(lds + (buf ^ 1) * 8192 + xwoff1) =
                pack8(nx2[0], nx2[1], nx2[2], nx2[3], nx3[0], nx3[1], nx3[2], nx3[3]);
        }
        __syncthreads();
    }

    const float qscale = 0.12752039f;   // log2(e)/sqrt(128)
    if (hd < 2) {
        unsigned short* dst = (hd == 0) ? Qs : Kb;
        const float sc = (hd == 0) ? qscale : 1.0f;
#pragma unroll
        for (int cf = 0; cf < 8; ++cf)
#pragma unroll
            for (int r = 0; r < 4; ++r) {
                const int row = m0 + wid * 16 + lgrp * 4 + r;
                const int col = cf * 16 + lrow;
                dst[(size_t)row * 128 + col] = f2bf(acc[cf][r] * sc);
            }
    } else {
#pragma unroll
        for (int cf = 0; cf < 8; ++cf) {
            const int row0 = m0 + wid * 16 + lgrp * 4;
            const int col  = cf * 16 + lrow;
            ushort4_ v;
#pragma unroll
            for (int r = 0; r < 4; r++) v[r] = f2bf(acc[cf][r]);
            *(ushort4_*)(Vt + (size_t)col * 8192 + row0) = v;
        }
    }
}

// ---------------------------------------------------------------------------
// Kernel 2: flash-attention partial — r12 structure, KVBLK 64->128 (8 iters).
// Block 512 = 8 waves x 32 q; q-tile 256 rows. grid 256 = 32 q-tiles x 8 sp.
// K tile [128 rows][256B] and V tile [128 d][256B] staged via global_load_lds
// w16 into 128KB dbuf LDS (sigma-permuted / XOR-swizzled SOURCE, linear dest;
// sigma extended by bit-6 passthrough, re-verified against QK->pa->PV chain).
// 8 glds/thread issued at iter top into buf^1; ONE __syncthreads per iter.
// ---------------------------------------------------------------------------
__global__ __launch_bounds__(512) void attn_kernel(
    const unsigned short* __restrict__ Qs,
    const unsigned short* __restrict__ Kb,
    const unsigned short* __restrict__ Vt,
    unsigned short* __restrict__ partO, float* __restrict__ partML)
{
    __shared__ __align__(16) char lds[131072];  // [buf][K 32KB | V 32KB]
    const int tid = threadIdx.x, lane = tid & 63, wid = tid >> 6;   // wid 0..7
    const int lrow = lane & 15, lgrp = lane >> 4;
    const int qtile = blockIdx.x >> 3, sp = blockIdx.x & 7;
    const int qb = qtile * 256 + wid * 32;
    const int kvstart = sp * 1024;

    // --- K staging: 4 glds/thread; 128 sigma-permuted rows, swizzled source ---
    const char* ksrc[4];
    int kdoff[4];
#pragma unroll
    for (int g = 0; g < 4; ++g) {
        const int slot = g * 32 + wid * 4 + lgrp;            // 0..127 bijective
        const int krow = (slot & 96) | (((slot >> 2) & 3) << 3)
                       | (((slot >> 4) & 1) << 2) | (slot & 3);
        ksrc[g] = (const char*)Kb + (size_t)(kvstart + krow) * 256
                + 16 * (lrow ^ (slot & 15));
        kdoff[g] = g * 8192 + wid * 1024;                    // + buf*65536
    }
    // --- V staging: 4 glds/thread; tile [128 d][256B], row-XOR swizzle ---
    const char* vsrc[4];
    int vdoff[4];
#pragma unroll
    for (int g = 0; g < 4; ++g) {
        const int drow = g * 32 + wid * 4 + lgrp;            // 0..127 bijective
        vsrc[g] = (const char*)Vt + (size_t)drow * 16384 + (size_t)kvstart * 2
                + ((lrow * 16) ^ ((drow & 7) << 4));
        vdoff[g] = g * 8192 + wid * 1024;                    // + buf*65536 + 32768
    }

    // Q fragments: lane holds Q[qb + j*16 + lrow][c*32 + lgrp*8 ..]
    short8 qf[2][4];
#pragma unroll
    for (int j = 0; j < 2; ++j)
#pragma unroll
        for (int c = 0; c < 4; ++c)
            qf[j][c] = *(const short8*)(Qs + (size_t)(qb + j * 16 + lrow) * 128 + c * 32 + lgrp * 8);

    f32x4 o[2][8];
#pragma unroll
    for (int j = 0; j < 2; ++j)
#pragma unroll
        for (int i = 0; i < 8; ++i) o[j][i] = (f32x4)0.0f;
    float m[2] = { -1e30f, -1e30f }, l[2] = { 0.0f, 0.0f };

    // prologue: tile 0 -> buf 0
#pragma unroll
    for (int g = 0; g < 4; ++g) GLOAD16(ksrc[g], lds + kdoff[g]);
#pragma unroll
    for (int g = 0; g < 4; ++g) GLOAD16(vsrc[g], lds + 32768 + vdoff[g]);
    __syncthreads();

    for (int t = 0; t < 8; ++t) {
        const int buf = t & 1;
        const char* kb = lds + buf * 65536;
        const char* vb = kb + 32768;

        // ---- issue next tile's 8 glds into buf^1 (fly through this iter) ----
        if (t < 7) {
            char* nk = lds + (buf ^ 1) * 65536;
#pragma unroll
            for (int g = 0; g < 4; ++g)
                GLOAD16(ksrc[g] + (size_t)(t + 1) * 32768, nk + kdoff[g]);
#pragma unroll
            for (int g = 0; g < 4; ++g)
                GLOAD16(vsrc[g] + (size_t)(t + 1) * 256, nk + 32768 + vdoff[g]);
        }

        // ---- S^T = K Q over 128 kv (exp2 domain; scale folded into Q) ----
        f32x4 s[2][8];
#pragma unroll
        for (int f = 0; f < 8; ++f) { s[0][f] = (f32x4)0.0f; s[1][f] = (f32x4)0.0f; }
        __builtin_amdgcn_s_setprio(1);
#pragma unroll
        for (int f = 0; f < 8; ++f) {
            const int rbase = (f * 16 + lrow) * 256;
            const int swz = lrow << 4;
#pragma unroll
            for (int c = 0; c < 4; ++c) {
                short8 kf = *(const short8*)(kb + rbase + ((c * 64 + lgrp * 16) ^ swz));
                s[0][f] = MFMA16(kf, qf[0][c], s[0][f]);
                s[1][f] = MFMA16(kf, qf[1][c], s[1][f]);
            }
        }
        __builtin_amdgcn_s_setprio(0);

        // ---- online softmax: lane owns q=lane&15 (per j);
        //      kv = (f>>2)*64 + ((f>>1)&1)*32 + 8*lgrp + 4*(f&1) + r ----
        float tm[2];
#pragma unroll
        for (int j = 0; j < 2; ++j) {
            float a0 = fmaxf(fmaxf(s[j][0][0], s[j][0][1]), fmaxf(s[j][0][2], s[j][0][3]));
            float a1 = fmaxf(fmaxf(s[j][1][0], s[j][1][1]), fmaxf(s[j][1][2], s[j][1][3]));
            float a2 = fmaxf(fmaxf(s[j][2][0], s[j][2][1]), fmaxf(s[j][2][2], s[j][2][3]));
            float a3 = fmaxf(fmaxf(s[j][3][0], s[j][3][1]), fmaxf(s[j][3][2], s[j][3][3]));
            float a4 = fmaxf(fmaxf(s[j][4][0], s[j][4][1]), fmaxf(s[j][4][2], s[j][4][3]));
            float a5 = fmaxf(fmaxf(s[j][5][0], s[j][5][1]), fmaxf(s[j][5][2], s[j][5][3]));
            float a6 = fmaxf(fmaxf(s[j][6][0], s[j][6][1]), fmaxf(s[j][6][2], s[j][6][3]));
            float a7 = fmaxf(fmaxf(s[j][7][0], s[j][7][1]), fmaxf(s[j][7][2], s[j][7][3]));
            float t2 = fmaxf(fmaxf(fmaxf(a0, a1), fmaxf(a2, a3)),
                             fmaxf(fmaxf(a4, a5), fmaxf(a6, a7)));
            t2 = fmaxf(t2, __shfl_xor(t2, 16));
            t2 = fmaxf(t2, __shfl_xor(t2, 32));
            tm[j] = t2;
        }
        const bool need = (tm[0] > m[0] + 8.0f) || (tm[1] > m[1] + 8.0f);
        if (__any(need)) {   // deferred-max rescale
#pragma unroll
            for (int j = 0; j < 2; ++j) {
                const float mn = fmaxf(m[j], tm[j]);
                const float al = exp2_fast(m[j] - mn);
                m[j] = mn;
                l[j] *= al;
#pragma unroll
                for (int r = 0; r < 4; ++r) {
                    const float ar = __shfl(al, lgrp * 4 + r);
#pragma unroll
                    for (int df = 0; df < 8; ++df) o[j][df][r] *= ar;
                }
            }
        }
        short8 pa[2][4];
#pragma unroll
        for (int j = 0; j < 2; ++j) {
            float rs = 0.0f;
#pragma unroll
            for (int f = 0; f < 8; ++f)
#pragma unroll
                for (int r = 0; r < 4; ++r) {
                    const float p = exp2_fast(s[j][f][r] - m[j]);
                    s[j][f][r] = p;
                    rs += p;
                }
            rs += __shfl_xor(rs, 16);
            rs += __shfl_xor(rs, 32);
            l[j] += rs;
#pragma unroll
            for (int ks = 0; ks < 4; ++ks)
                pa[j][ks] = pack8(s[j][2 * ks][0], s[j][2 * ks][1], s[j][2 * ks][2], s[j][2 * ks][3],
                                  s[j][2 * ks + 1][0], s[j][2 * ks + 1][1], s[j][2 * ks + 1][2], s[j][2 * ks + 1][3]);
        }

        // ---- O += P V (V from LDS; 32 reads, 64 MFMA) ----
        __builtin_amdgcn_s_setprio(1);
#pragma unroll
        for (int ks = 0; ks < 4; ++ks) {
#pragma unroll
            for (int df = 0; df < 8; ++df) {
                const int d = df * 16 + lrow;
                short8 vf = *(const short8*)(vb + d * 256 +
                              ((ks * 64 + lgrp * 16) ^ ((d & 7) << 4)));
                o[0][df] = MFMA16(pa[0][ks], vf, o[0][df]);
                o[1][df] = MFMA16(pa[1][ks], vf, o[1][df]);
            }
        }
        __builtin_amdgcn_s_setprio(0);

        __syncthreads();   // drains this iter's glds; orders buf swap
    }

    // ---- state to row form (row = j*16 + lgrp*4 + r) ----
    float mr[2][4], lr_[2][4];
#pragma unroll
    for (int j = 0; j < 2; ++j)
#pragma unroll
        for (int r = 0; r < 4; ++r) {
            mr[j][r]  = __shfl(m[j], lgrp * 4 + r);
            lr_[j][r] = __shfl(l[j], lgrp * 4 + r);
        }

    // ---- write bf16 unnormalized partial + f32 (m,l) ----
#pragma unroll
    for (int j = 0; j < 2; ++j)
#pragma unroll
        for (int df = 0; df < 8; ++df)
#pragma unroll
            for (int r = 0; r < 4; ++r) {
                const int qg = qb + j * 16 + lgrp * 4 + r;
                partO[((size_t)sp * 8192 + qg) * 128 + df * 16 + lrow] = f2bf(o[j][df][r]);
            }
    if (lrow == 0) {
#pragma unroll
        for (int j = 0; j < 2; ++j)
#pragma unroll
            for (int r = 0; r < 4; ++r) {
                const int qg = qb + j * 16 + lgrp * 4 + r;
                partML[((size_t)sp * 8192 + qg) * 2]     = mr[j][r];
                partML[((size_t)sp * 8192 + qg) * 2 + 1] = lr_[j][r];
            }
    }
}

// ---------------------------------------------------------------------------
// Kernel 3: merge 8 kv-split bf16 partials and normalize.
// ---------------------------------------------------------------------------
__global__ __launch_bounds__(256) void merge_kernel(
    const unsigned short* __restrict__ partO, const float* __restrict__ partML,
    float* __restrict__ out)
{
    const int gid = blockIdx.x * 256 + threadIdx.x;   // 0..262143
    const int q = gid >> 5, dc = gid & 31;
    float mv[8], lv[8];
#pragma unroll
    for (int spv = 0; spv < 8; ++spv) {
        mv[spv] = partML[((size_t)spv * 8192 + q) * 2];
        lv[spv] = partML[((size_t)spv * 8192 + q) * 2 + 1];
    }
    float M = mv[0];
#pragma unroll
    for (int spv = 1; spv < 8; ++spv) M = fmaxf(M, mv[spv]);
    float e[8], L = 0.f;
#pragma unroll
    for (int spv = 0; spv < 8; ++spv) { e[spv] = exp2_fast(mv[spv] - M); L += lv[spv] * e[spv]; }
    const float inv = 1.0f / L;
    f32x4 r = (f32x4)0.0f;
#pragma unroll
    for (int spv = 0; spv < 8; ++spv) {
        ushort4_ v = *(const ushort4_*)(partO + ((size_t)spv * 8192 + q) * 128 + dc * 4);
#pragma unroll
        for (int k = 0; k < 4; ++k) r[k] += bf2f(v[k]) * e[spv];
    }
#pragma unroll
    for (int k = 0; k < 4; ++k) r[k] *= inv;
    *(f32x4*)(out + (size_t)q * 128 + dc * 4) = r;
}

extern "C" void kernel_launch(void* const* d_in, const int* in_sizes, int n_in,
                              void* d_out, int out_size, void* d_ws, size_t ws_size,
                              hipStream_t stream)
{
    const float* X  = (const float*)d_in[0];
    const float* Wq = (const float*)d_in[1];
    const float* Wk = (const float*)d_in[2];
    const float* Wv = (const float*)d_in[3];

    char* ws = (char*)d_ws;
    const size_t QS_OFF  = 0;                                   // 2 MiB
    const size_t KB_OFF  = QS_OFF + (size_t)8192 * 128 * 2;     // 2 MiB
    const size_t VT_OFF  = KB_OFF + (size_t)8192 * 128 * 2;     // 2 MiB (V transposed)
    const size_t WB_OFF  = VT_OFF + (size_t)8192 * 128 * 2;     // 768 KiB
    const size_t PO_OFF  = WB_OFF + (size_t)3 * 128 * 1024 * 2; // 8*8192*128 bf16 = 16 MiB
    const size_t PML_OFF = PO_OFF + (size_t)8 * 8192 * 128 * 2; // 8*8192*2 f32 = 512 KiB

    unsigned short* Qs  = (unsigned short*)(ws + QS_OFF);
    unsigned short* Kb  = (unsigned short*)(ws + KB_OFF);
    unsigned short* Vt  = (unsigned short*)(ws + VT_OFF);
    unsigned short* Wb  = (unsigned short*)(ws + WB_OFF);
    unsigned short* partO = (unsigned short*)(ws + PO_OFF);
    float* partML = (float*)(ws + PML_OFF);
    float* out = (float*)d_out;

    wcvt_kernel<<<dim3(128, 3), 256, 0, stream>>>(Wq, Wk, Wv, Wb);
    qkv_kernel<<<dim3(128, 3), 256, 0, stream>>>(X, Wb, Qs, Kb, Vt);
    attn_kernel<<<dim3(256), 512, 0, stream>>>(Qs, Kb, Vt, partO, partML);
    merge_kernel<<<dim3(1024), 256, 0, stream>>>(partO, partML, out);
}

// Round 14
// 71.196 us; speedup vs baseline: 2.2755x; 1.0053x over previous
//
#include <hip/hip_runtime.h>
#include <stdint.h>

typedef __attribute__((ext_vector_type(8))) short short8;       // 8 x bf16
typedef __attribute__((ext_vector_type(4))) float f32x4;
typedef __attribute__((ext_vector_type(4))) unsigned short ushort4_;
typedef __attribute__((ext_vector_type(4))) unsigned int uint4_;

#define MFMA16(a, b, c) __builtin_amdgcn_mfma_f32_16x16x32_bf16((a), (b), (c), 0, 0, 0)

static __device__ __forceinline__ unsigned short f2bf(float f) {
    unsigned u = __float_as_uint(f);
    u += 0x7fffu + ((u >> 16) & 1u);   // RNE
    return (unsigned short)(u >> 16);
}

static __device__ __forceinline__ float bf2f(unsigned short u) {
    return __uint_as_float(((unsigned)u) << 16);
}

static __device__ __forceinline__ float exp2_fast(float x) {
#if __has_builtin(__builtin_amdgcn_exp2f)
    return __builtin_amdgcn_exp2f(x);
#else
    return exp2f(x);
#endif
}

static __device__ __forceinline__ unsigned cvt_pk(float lo, float hi) {
    unsigned r;
    asm("v_cvt_pk_bf16_f32 %0, %1, %2" : "=v"(r) : "v"(lo), "v"(hi));
    return r;
}

static __device__ __forceinline__ short8 pack8(float a0, float a1, float a2, float a3,
                                               float a4, float a5, float a6, float a7) {
    union { uint4_ u; short8 s; } c;
    c.u[0] = cvt_pk(a0, a1); c.u[1] = cvt_pk(a2, a3);
    c.u[2] = cvt_pk(a4, a5); c.u[3] = cvt_pk(a6, a7);
    return c.s;
}

#define GLOAD16(SRC, DSTPTR) __builtin_amdgcn_global_load_lds(                       \
    (const __attribute__((address_space(1))) void*)(SRC),                            \
    (__attribute__((address_space(3))) void*)(DSTPTR), 16, 0, 0)

// ---------------------------------------------------------------------------
// Kernel 0: W (3 heads, f32) -> bf16, contiguous Wb[3][128][1024]
// ---------------------------------------------------------------------------
__global__ __launch_bounds__(256) void wcvt_kernel(
    const float* __restrict__ Wq, const float* __restrict__ Wk, const float* __restrict__ Wv,
    unsigned short* __restrict__ Wb)
{
    const int hd = blockIdx.y;
    const float* W = (hd == 0) ? Wq : ((hd == 1) ? Wk : Wv);
    const int idx = (blockIdx.x * 256 + threadIdx.x) * 4;
    f32x4 v = *(const f32x4*)(W + idx);
    ushort4_ o;
#pragma unroll
    for (int j = 0; j < 4; ++j) o[j] = f2bf(v[j]);
    *(ushort4_*)(Wb + (size_t)hd * 131072 + idx) = o;
}

// ---------------------------------------------------------------------------
// Kernel 1: QKV projection (r9 version — best measured).
// Per-head blocks: grid (128, 3), M-tile 64, 4 waves x 16 rows. K-step 64,
// 16 steps, ONE __syncthreads per step. W via global_load_lds w16 (swizzled
// source); X f32 reg-staged (T14). LDS 48KB -> 3 blocks/CU.
//   head0: Q * log2(e)/sqrt(128) -> Qs ; head1: K -> Kb ; head2: V -> Vt^T
// ---------------------------------------------------------------------------
__global__ __launch_bounds__(256) void qkv_kernel(
    const float* __restrict__ X, const unsigned short* __restrict__ Wb,
    unsigned short* __restrict__ Qs, unsigned short* __restrict__ Kb, unsigned short* __restrict__ Vt)
{
    __shared__ __align__(16) char lds[49152];   // X dbuf 2x8KB @0; W dbuf 2x16KB @16384
    const int tid  = threadIdx.x;
    const int lane = tid & 63, wid = tid >> 6;
    const int lrow = lane & 15, lgrp = lane >> 4;
    const int m0   = blockIdx.x * 64;
    const int hd   = blockIdx.y;
    const unsigned short* W = Wb + (size_t)hd * 131072;

    const char* wsrc[4];
    int wdoff[4];
#pragma unroll
    for (int g = 0; g < 4; ++g) {
        const int slot = g * 256 + tid;          // 0..1023
        const int row = slot >> 3, c16 = slot & 7;
        wsrc[g] = (const char*)(W + (size_t)row * 1024) + 16 * (c16 ^ (row & 7));
        wdoff[g] = g * 4096 + wid * 1024;
    }
    const int xrow = tid >> 2, xseg = tid & 3;   // 64 rows x 4 segs x 16 f32
    const float* xbase = X + (size_t)(m0 + xrow) * 1024 + xseg * 16;
    const int xsw = (xrow & 7) << 4;
    const int xwoff0 = xrow * 128 + (((xseg * 2)     * 16) ^ xsw);
    const int xwoff1 = xrow * 128 + (((xseg * 2 + 1) * 16) ^ xsw);

    f32x4 acc[8];
#pragma unroll
    for (int b = 0; b < 8; b++) acc[b] = (f32x4)0.0f;

#pragma unroll
    for (int g = 0; g < 4; ++g) GLOAD16(wsrc[g], lds + 16384 + wdoff[g]);
    {
        f32x4 x0 = *(const f32x4*)(xbase);
        f32x4 x1 = *(const f32x4*)(xbase + 4);
        f32x4 x2 = *(const f32x4*)(xbase + 8);
        f32x4 x3 = *(const f32x4*)(xbase + 12);
        *(short8*)(lds + xwoff0) = pack8(x0[0], x0[1], x0[2], x0[3], x1[0], x1[1], x1[2], x1[3]);
        *(short8*)(lds + xwoff1) = pack8(x2[0], x2[1], x2[2], x2[3], x3[0], x3[1], x3[2], x3[3]);
    }
    __syncthreads();

    for (int ks = 0; ks < 16; ++ks) {
        const int buf = ks & 1;
        f32x4 nx0, nx1, nx2, nx3;
        if (ks < 15) {
#pragma unroll
            for (int g = 0; g < 4; ++g)
                GLOAD16(wsrc[g] + (size_t)(ks + 1) * 128, lds + 16384 + (buf ^ 1) * 16384 + wdoff[g]);
            nx0 = *(const f32x4*)(xbase + (ks + 1) * 64);
            nx1 = *(const f32x4*)(xbase + (ks + 1) * 64 + 4);
            nx2 = *(const f32x4*)(xbase + (ks + 1) * 64 + 8);
            nx3 = *(const f32x4*)(xbase + (ks + 1) * 64 + 12);
        }
        const char* xb  = lds + buf * 8192;
        const char* wbl = lds + 16384 + buf * 16384;
        __builtin_amdgcn_s_setprio(1);
#pragma unroll
        for (int kc = 0; kc < 2; ++kc) {
            const int arow = wid * 16 + lrow;
            const int koff = (kc * 64 + lgrp * 16) ^ ((lrow & 7) << 4);
            short8 a = *(const short8*)(xb + arow * 128 + koff);
#pragma unroll
            for (int cf = 0; cf < 8; ++cf) {
                const int n = cf * 16 + lrow;
                short8 b = *(const short8*)(wbl + n * 128 + koff);
                acc[cf] = MFMA16(a, b, acc[cf]);
            }
        }
        __builtin_amdgcn_s_setprio(0);
        if (ks < 15) {
            *(short8*)(lds + (buf ^ 1) * 8192 + xwoff0) =
                pack8(nx0[0], nx0[1], nx0[2], nx0[3], nx1[0], nx1[1], nx1[2], nx1[3]);
            *(short8*)(lds + (buf ^ 1) * 8192 + xwoff1) =
                pack8(nx2[0], nx2[1], nx2[2], nx2[3], nx3[0], nx3[1], nx3[2], nx3[3]);
        }
        __syncthreads();
    }

    const float qscale = 0.12752039f;   // log2(e)/sqrt(128)
    if (hd < 2) {
        unsigned short* dst = (hd == 0) ? Qs : Kb;
        const float sc = (hd == 0) ? qscale : 1.0f;
#pragma unroll
        for (int cf = 0; cf < 8; ++cf)
#pragma unroll
            for (int r = 0; r < 4; ++r) {
                const int row = m0 + wid * 16 + lgrp * 4 + r;
                const int col = cf * 16 + lrow;
                dst[(size_t)row * 128 + col] = f2bf(acc[cf][r] * sc);
            }
    } else {
#pragma unroll
        for (int cf = 0; cf < 8; ++cf) {
            const int row0 = m0 + wid * 16 + lgrp * 4;
            const int col  = cf * 16 + lrow;
            ushort4_ v;
#pragma unroll
            for (int r = 0; r < 4; r++) v[r] = f2bf(acc[cf][r]);
            *(ushort4_*)(Vt + (size_t)col * 8192 + row0) = v;
        }
    }
}

// ---------------------------------------------------------------------------
// Kernel 2: flash-attention partial — r13 structure (KVBLK=128, 8 iters),
// with the V-tile swizzle widened 3->4 bits ((d&15)<<4) to match K's
// conflict-free pattern at 256B rows (r13 regression: 2.1M conflict cycles
// from the stale 3-bit swizzle). Block 512 = 8 waves x 32 q; q-tile 256.
// grid 256 = 32 q-tiles x 8 sp. K/V staged via global_load_lds w16 into
// 128KB dbuf LDS (sigma-permuted / XOR-swizzled SOURCE, linear dest).
// ---------------------------------------------------------------------------
__global__ __launch_bounds__(512) void attn_kernel(
    const unsigned short* __restrict__ Qs,
    const unsigned short* __restrict__ Kb,
    const unsigned short* __restrict__ Vt,
    unsigned short* __restrict__ partO, float* __restrict__ partML)
{
    __shared__ __align__(16) char lds[131072];  // [buf][K 32KB | V 32KB]
    const int tid = threadIdx.x, lane = tid & 63, wid = tid >> 6;   // wid 0..7
    const int lrow = lane & 15, lgrp = lane >> 4;
    const int qtile = blockIdx.x >> 3, sp = blockIdx.x & 7;
    const int qb = qtile * 256 + wid * 32;
    const int kvstart = sp * 1024;

    // --- K staging: 4 glds/thread; 128 sigma-permuted rows, swizzled source ---
    const char* ksrc[4];
    int kdoff[4];
#pragma unroll
    for (int g = 0; g < 4; ++g) {
        const int slot = g * 32 + wid * 4 + lgrp;            // 0..127 bijective
        const int krow = (slot & 96) | (((slot >> 2) & 3) << 3)
                       | (((slot >> 4) & 1) << 2) | (slot & 3);
        ksrc[g] = (const char*)Kb + (size_t)(kvstart + krow) * 256
                + 16 * (lrow ^ (slot & 15));
        kdoff[g] = g * 8192 + wid * 1024;                    // + buf*65536
    }
    // --- V staging: 4 glds/thread; tile [128 d][256B], 4-bit row-XOR swizzle ---
    const char* vsrc[4];
    int vdoff[4];
#pragma unroll
    for (int g = 0; g < 4; ++g) {
        const int drow = g * 32 + wid * 4 + lgrp;            // 0..127 bijective
        vsrc[g] = (const char*)Vt + (size_t)drow * 16384 + (size_t)kvstart * 2
                + ((lrow * 16) ^ ((drow & 15) << 4));
        vdoff[g] = g * 8192 + wid * 1024;                    // + buf*65536 + 32768
    }

    // Q fragments: lane holds Q[qb + j*16 + lrow][c*32 + lgrp*8 ..]
    short8 qf[2][4];
#pragma unroll
    for (int j = 0; j < 2; ++j)
#pragma unroll
        for (int c = 0; c < 4; ++c)
            qf[j][c] = *(const short8*)(Qs + (size_t)(qb + j * 16 + lrow) * 128 + c * 32 + lgrp * 8);

    f32x4 o[2][8];
#pragma unroll
    for (int j = 0; j < 2; ++j)
#pragma unroll
        for (int i = 0; i < 8; ++i) o[j][i] = (f32x4)0.0f;
    float m[2] = { -1e30f, -1e30f }, l[2] = { 0.0f, 0.0f };

    // prologue: tile 0 -> buf 0
#pragma unroll
    for (int g = 0; g < 4; ++g) GLOAD16(ksrc[g], lds + kdoff[g]);
#pragma unroll
    for (int g = 0; g < 4; ++g) GLOAD16(vsrc[g], lds + 32768 + vdoff[g]);
    __syncthreads();

    for (int t = 0; t < 8; ++t) {
        const int buf = t & 1;
        const char* kb = lds + buf * 65536;
        const char* vb = kb + 32768;

        // ---- issue next tile's 8 glds into buf^1 (fly through this iter) ----
        if (t < 7) {
            char* nk = lds + (buf ^ 1) * 65536;
#pragma unroll
            for (int g = 0; g < 4; ++g)
                GLOAD16(ksrc[g] + (size_t)(t + 1) * 32768, nk + kdoff[g]);
#pragma unroll
            for (int g = 0; g < 4; ++g)
                GLOAD16(vsrc[g] + (size_t)(t + 1) * 256, nk + 32768 + vdoff[g]);
        }

        // ---- S^T = K Q over 128 kv (exp2 domain; scale folded into Q) ----
        f32x4 s[2][8];
#pragma unroll
        for (int f = 0; f < 8; ++f) { s[0][f] = (f32x4)0.0f; s[1][f] = (f32x4)0.0f; }
        __builtin_amdgcn_s_setprio(1);
#pragma unroll
        for (int f = 0; f < 8; ++f) {
            const int rbase = (f * 16 + lrow) * 256;
            const int swz = lrow << 4;
#pragma unroll
            for (int c = 0; c < 4; ++c) {
                short8 kf = *(const short8*)(kb + rbase + ((c * 64 + lgrp * 16) ^ swz));
                s[0][f] = MFMA16(kf, qf[0][c], s[0][f]);
                s[1][f] = MFMA16(kf, qf[1][c], s[1][f]);
            }
        }
        __builtin_amdgcn_s_setprio(0);

        // ---- online softmax: lane owns q=lane&15 (per j);
        //      kv = (f>>2)*64 + ((f>>1)&1)*32 + 8*lgrp + 4*(f&1) + r ----
        float tm[2];
#pragma unroll
        for (int j = 0; j < 2; ++j) {
            float a0 = fmaxf(fmaxf(s[j][0][0], s[j][0][1]), fmaxf(s[j][0][2], s[j][0][3]));
            float a1 = fmaxf(fmaxf(s[j][1][0], s[j][1][1]), fmaxf(s[j][1][2], s[j][1][3]));
            float a2 = fmaxf(fmaxf(s[j][2][0], s[j][2][1]), fmaxf(s[j][2][2], s[j][2][3]));
            float a3 = fmaxf(fmaxf(s[j][3][0], s[j][3][1]), fmaxf(s[j][3][2], s[j][3][3]));
            float a4 = fmaxf(fmaxf(s[j][4][0], s[j][4][1]), fmaxf(s[j][4][2], s[j][4][3]));
            float a5 = fmaxf(fmaxf(s[j][5][0], s[j][5][1]), fmaxf(s[j][5][2], s[j][5][3]));
            float a6 = fmaxf(fmaxf(s[j][6][0], s[j][6][1]), fmaxf(s[j][6][2], s[j][6][3]));
            float a7 = fmaxf(fmaxf(s[j][7][0], s[j][7][1]), fmaxf(s[j][7][2], s[j][7][3]));
            float t2 = fmaxf(fmaxf(fmaxf(a0, a1), fmaxf(a2, a3)),
                             fmaxf(fmaxf(a4, a5), fmaxf(a6, a7)));
            t2 = fmaxf(t2, __shfl_xor(t2, 16));
            t2 = fmaxf(t2, __shfl_xor(t2, 32));
            tm[j] = t2;
        }
        const bool need = (tm[0] > m[0] + 8.0f) || (tm[1] > m[1] + 8.0f);
        if (__any(need)) {   // deferred-max rescale
#pragma unroll
            for (int j = 0; j < 2; ++j) {
                const float mn = fmaxf(m[j], tm[j]);
                const float al = exp2_fast(m[j] - mn);
                m[j] = mn;
                l[j] *= al;
#pragma unroll
                for (int r = 0; r < 4; ++r) {
                    const float ar = __shfl(al, lgrp * 4 + r);
#pragma unroll
                    for (int df = 0; df < 8; ++df) o[j][df][r] *= ar;
                }
            }
        }
        short8 pa[2][4];
#pragma unroll
        for (int j = 0; j < 2; ++j) {
            float rs = 0.0f;
#pragma unroll
            for (int f = 0; f < 8; ++f)
#pragma unroll
                for (int r = 0; r < 4; ++r) {
                    const float p = exp2_fast(s[j][f][r] - m[j]);
                    s[j][f][r] = p;
                    rs += p;
                }
            rs += __shfl_xor(rs, 16);
            rs += __shfl_xor(rs, 32);
            l[j] += rs;
#pragma unroll
            for (int ks = 0; ks < 4; ++ks)
                pa[j][ks] = pack8(s[j][2 * ks][0], s[j][2 * ks][1], s[j][2 * ks][2], s[j][2 * ks][3],
                                  s[j][2 * ks + 1][0], s[j][2 * ks + 1][1], s[j][2 * ks + 1][2], s[j][2 * ks + 1][3]);
        }

        // ---- O += P V (V from LDS; 32 reads, 64 MFMA; 4-bit XOR) ----
        __builtin_amdgcn_s_setprio(1);
#pragma unroll
        for (int ks = 0; ks < 4; ++ks) {
#pragma unroll
            for (int df = 0; df < 8; ++df) {
                const int d = df * 16 + lrow;
                short8 vf = *(const short8*)(vb + d * 256 +
                              ((ks * 64 + lgrp * 16) ^ ((d & 15) << 4)));
                o[0][df] = MFMA16(pa[0][ks], vf, o[0][df]);
                o[1][df] = MFMA16(pa[1][ks], vf, o[1][df]);
            }
        }
        __builtin_amdgcn_s_setprio(0);

        __syncthreads();   // drains this iter's glds; orders buf swap
    }

    // ---- state to row form (row = j*16 + lgrp*4 + r) ----
    float mr[2][4], lr_[2][4];
#pragma unroll
    for (int j = 0; j < 2; ++j)
#pragma unroll
        for (int r = 0; r < 4; ++r) {
            mr[j][r]  = __shfl(m[j], lgrp * 4 + r);
            lr_[j][r] = __shfl(l[j], lgrp * 4 + r);
        }

    // ---- write bf16 unnormalized partial + f32 (m,l) ----
#pragma unroll
    for (int j = 0; j < 2; ++j)
#pragma unroll
        for (int df = 0; df < 8; ++df)
#pragma unroll
            for (int r = 0; r < 4; ++r) {
                const int qg = qb + j * 16 + lgrp * 4 + r;
                partO[((size_t)sp * 8192 + qg) * 128 + df * 16 + lrow] = f2bf(o[j][df][r]);
            }
    if (lrow == 0) {
#pragma unroll
        for (int j = 0; j < 2; ++j)
#pragma unroll
            for (int r = 0; r < 4; ++r) {
                const int qg = qb + j * 16 + lgrp * 4 + r;
                partML[((size_t)sp * 8192 + qg) * 2]     = mr[j][r];
                partML[((size_t)sp * 8192 + qg) * 2 + 1] = lr_[j][r];
            }
    }
}

// ---------------------------------------------------------------------------
// Kernel 3: merge 8 kv-split bf16 partials and normalize.
// ---------------------------------------------------------------------------
__global__ __launch_bounds__(256) void merge_kernel(
    const unsigned short* __restrict__ partO, const float* __restrict__ partML,
    float* __restrict__ out)
{
    const int gid = blockIdx.x * 256 + threadIdx.x;   // 0..262143
    const int q = gid >> 5, dc = gid & 31;
    float mv[8], lv[8];
#pragma unroll
    for (int spv = 0; spv < 8; ++spv) {
        mv[spv] = partML[((size_t)spv * 8192 + q) * 2];
        lv[spv] = partML[((size_t)spv * 8192 + q) * 2 + 1];
    }
    float M = mv[0];
#pragma unroll
    for (int spv = 1; spv < 8; ++spv) M = fmaxf(M, mv[spv]);
    float e[8], L = 0.f;
#pragma unroll
    for (int spv = 0; spv < 8; ++spv) { e[spv] = exp2_fast(mv[spv] - M); L += lv[spv] * e[spv]; }
    const float inv = 1.0f / L;
    f32x4 r = (f32x4)0.0f;
#pragma unroll
    for (int spv = 0; spv < 8; ++spv) {
        ushort4_ v = *(const ushort4_*)(partO + ((size_t)spv * 8192 + q) * 128 + dc * 4);
#pragma unroll
        for (int k = 0; k < 4; ++k) r[k] += bf2f(v[k]) * e[spv];
    }
#pragma unroll
    for (int k = 0; k < 4; ++k) r[k] *= inv;
    *(f32x4*)(out + (size_t)q * 128 + dc * 4) = r;
}

extern "C" void kernel_launch(void* const* d_in, const int* in_sizes, int n_in,
                              void* d_out, int out_size, void* d_ws, size_t ws_size,
                              hipStream_t stream)
{
    const float* X  = (const float*)d_in[0];
    const float* Wq = (const float*)d_in[1];
    const float* Wk = (const float*)d_in[2];
    const float* Wv = (const float*)d_in[3];

    char* ws = (char*)d_ws;
    const size_t QS_OFF  = 0;                                   // 2 MiB
    const size_t KB_OFF  = QS_OFF + (size_t)8192 * 128 * 2;     // 2 MiB
    const size_t VT_OFF  = KB_OFF + (size_t)8192 * 128 * 2;     // 2 MiB (V transposed)
    const size_t WB_OFF  = VT_OFF + (size_t)8192 * 128 * 2;     // 768 KiB
    const size_t PO_OFF  = WB_OFF + (size_t)3 * 128 * 1024 * 2; // 8*8192*128 bf16 = 16 MiB
    const size_t PML_OFF = PO_OFF + (size_t)8 * 8192 * 128 * 2; // 8*8192*2 f32 = 512 KiB

    unsigned short* Qs  = (unsigned short*)(ws + QS_OFF);
    unsigned short* Kb  = (unsigned short*)(ws + KB_OFF);
    unsigned short* Vt  = (unsigned short*)(ws + VT_OFF);
    unsigned short* Wb  = (unsigned short*)(ws + WB_OFF);
    unsigned short* partO = (unsigned short*)(ws + PO_OFF);
    float* partML = (float*)(ws + PML_OFF);
    float* out = (float*)d_out;

    wcvt_kernel<<<dim3(128, 3), 256, 0, stream>>>(Wq, Wk, Wv, Wb);
    qkv_kernel<<<dim3(128, 3), 256, 0, stream>>>(X, Wb, Qs, Kb, Vt);
    attn_kernel<<<dim3(256), 512, 0, stream>>>(Qs, Kb, Vt, partO, partML);
    merge_kernel<<<dim3(1024), 256, 0, stream>>>(partO, partML, out);
}